// Round 3
// baseline (25229.686 us; speedup 1.0000x reference)
//
#include <hip/hip_runtime.h>

typedef _Float16 f16;
typedef _Float16 f16x8 __attribute__((ext_vector_type(8)));
typedef _Float16 f16x4 __attribute__((ext_vector_type(4)));
typedef float f32x4 __attribute__((ext_vector_type(4)));

#define DEVFN static __device__ __forceinline__

#define NBLK 160
#define NGATE 128

// ---------------- workspace layout (bytes) ----------------
#define OFF_WCAT 0ULL                          // 2048*768*2   = 3 MB
#define OFF_WT1  (OFF_WCAT + 2048ULL*768*2)    // 512*1024*2   = 1 MB
#define OFF_A    (OFF_WT1  + 512ULL*1024*2)    // 256*1280*2   = 640 KB
#define OFF_GATES (OFF_A   + 256ULL*1280*2)    // 256*2048*4   = 2 MB
#define OFF_BSUM (OFF_GATES + 256ULL*2048*4)   // 2048*4
#define OFF_U    (OFF_BSUM + 2048ULL*4)        // 512*256*4
#define OFF_V    (OFF_U    + 512ULL*256*4)
#define OFF_CU   (OFF_V    + 512ULL*256*4)
#define OFF_CV   (OFF_CU   + 512ULL*4)
#define OFF_ZETA (OFF_CV   + 512ULL*4)
#define OFF_RES  (OFF_ZETA + 512ULL*4)         // 512*256*4
#define OFF_TENS (OFF_RES  + 512ULL*256*4)     // 2*256*4
#define OFF_BAR  (OFF_TENS + 2ULL*256*4)       // 160*32*4 arrival + flag

__constant__ float CGAM[15] = {14.134725f, 21.02204f, 25.010858f, 30.424876f, 32.935062f,
  37.586178f, 40.91872f, 43.327073f, 48.005151f, 49.773832f, 52.970321f,
  56.446248f, 59.347044f, 60.831779f, 65.112544f};

DEVFN float sigf(float v) { return 1.f / (1.f + __expf(-v)); }
DEVFN float tanh_(float v) {
  v = fminf(fmaxf(v, -15.f), 15.f);
  float e = __expf(2.f * v);
  return (e - 1.f) / (e + 1.f);
}

DEVFN void gl_lds16(const void* g, void* l) {
  __builtin_amdgcn_global_load_lds((__attribute__((address_space(1))) void*)g,
                                   (__attribute__((address_space(3))) void*)l, 16, 0, 0);
}

// grid barrier: per-block arrival lines (release) + block0 aggregates -> epoch flag.
DEVFN void gbar(unsigned* arr, unsigned* flag, unsigned e) {
  __syncthreads();
  if (threadIdx.x == 0) {
    __threadfence();
    __hip_atomic_store(arr + blockIdx.x * 32, e, __ATOMIC_RELEASE, __HIP_MEMORY_SCOPE_AGENT);
  }
  if (blockIdx.x == 0) {
    if (threadIdx.x < NBLK) {
      unsigned* p = arr + threadIdx.x * 32;
      long sp = 0;
      while (__hip_atomic_load(p, __ATOMIC_ACQUIRE, __HIP_MEMORY_SCOPE_AGENT) < e) {
        __builtin_amdgcn_s_sleep(1);
        if (++sp > (1L << 24)) break;
      }
    }
    __syncthreads();
    if (threadIdx.x == 0)
      __hip_atomic_store(flag, e, __ATOMIC_RELEASE, __HIP_MEMORY_SCOPE_AGENT);
  }
  if (threadIdx.x == 0) {
    long sp = 0;
    while (__hip_atomic_load(flag, __ATOMIC_ACQUIRE, __HIP_MEMORY_SCOPE_AGENT) < e) {
      __builtin_amdgcn_s_sleep(1);
      if (++sp > (1L << 24)) break;
    }
    __threadfence();
  }
  __syncthreads();
}

// ---------------- init: weight conversion + state zeroing ----------------
__global__ void k_init(const float* __restrict__ x, const float* __restrict__ Wih,
                       const float* __restrict__ Whh, const float* __restrict__ bih,
                       const float* __restrict__ bhh, const float* __restrict__ Wt1f,
                       char* __restrict__ ws) {
  f16* Wcat = (f16*)(ws + OFF_WCAT);
  f16* Wt1h = (f16*)(ws + OFF_WT1);
  f16* A    = (f16*)(ws + OFF_A);
  float* bsum = (float*)(ws + OFF_BSUM);
  float* tens = (float*)(ws + OFF_TENS);
  unsigned* bar = (unsigned*)(ws + OFF_BAR);
  int gtid = blockIdx.x * blockDim.x + threadIdx.x;
  int nth = gridDim.x * blockDim.x;
  for (int i = gtid; i < 2048 * 768; i += nth) {
    int n = i / 768, k = i - n * 768;
    float w = (k < 256) ? Wih[n * 256 + k] : Whh[n * 512 + (k - 256)];
    Wcat[i] = (f16)w;
  }
  for (int i = gtid; i < 512 * 1024; i += nth) Wt1h[i] = (f16)Wt1f[i];
  for (int i = gtid; i < 2048; i += nth) bsum[i] = bih[i] + bhh[i];
  for (int i = gtid; i < 256 * 1280; i += nth) {
    int b = i / 1280, k = i - b * 1280;
    A[i] = (k < 256) ? (f16)x[(size_t)b * 131072 + k] : (f16)0.f;  // x[b][0][k]; h,hmean = 0
  }
  for (int i = gtid; i < 512; i += nth) tens[i] = 0.f;
  for (int i = gtid; i < NBLK * 32 + 32; i += nth) bar[i] = 0u;
}

// ---------------- per-t tables ----------------
__global__ void k_tables(const float* __restrict__ Wproj, const float* __restrict__ bproj,
                         char* __restrict__ ws) {
  float* u    = (float*)(ws + OFF_U);
  float* v    = (float*)(ws + OFF_V);
  float* cu   = (float*)(ws + OFF_CU);
  float* cv   = (float*)(ws + OFF_CV);
  float* zeta = (float*)(ws + OFF_ZETA);
  int t = blockIdx.x;
  int k = threadIdx.x;
  float tf = (float)t;
  float cg[15], sg[15], ph[15];
  #pragma unroll
  for (int m = 0; m < 15; ++m) {
    float ang = CGAM[m] * tf;
    cg[m] = cosf(ang);
    sg[m] = sinf(ang);
    ph[m] = (float)exp(-0.1 * (double)CGAM[m]);
  }
  float uu = 0.f, vv = 0.f;
  #pragma unroll
  for (int m = 0; m < 15; ++m) {
    uu += Wproj[m * 256 + k] * cg[m] * ph[m];
    vv += Wproj[(15 + m) * 256 + k] * sg[m] * ph[m];
  }
  u[t * 256 + k] = uu;
  v[t * 256 + k] = vv;
  if (k == 0) {
    float a = 0.f, b2 = 0.f, z = 0.f;
    #pragma unroll
    for (int m = 0; m < 15; ++m) {
      a  += bproj[m] * cg[m] * ph[m];
      b2 += bproj[15 + m] * sg[m] * ph[m];
      z  += ph[m] * cg[m];
    }
    cu[t] = a; cv[t] = b2; zeta[t] = z / 15.f;
  }
}

// ---------------- resonance[b,t] precompute ----------------
__global__ void k_res(const float* __restrict__ x, char* __restrict__ ws) {
  const float* u  = (const float*)(ws + OFF_U);
  const float* v  = (const float*)(ws + OFF_V);
  const float* cu = (const float*)(ws + OFF_CU);
  const float* cv = (const float*)(ws + OFF_CV);
  float* resb     = (float*)(ws + OFF_RES);
  int wid = blockIdx.x * 4 + (threadIdx.x >> 6);
  int l = threadIdx.x & 63;
  int b = wid >> 9, t = wid & 511;
  const f32x4 xx = *(const f32x4*)(x + ((size_t)(b * 512 + t)) * 256 + l * 4);
  const f32x4 uu = *(const f32x4*)(u + t * 256 + l * 4);
  const f32x4 vv = *(const f32x4*)(v + t * 256 + l * 4);
  float cc = xx[0]*uu[0] + xx[1]*uu[1] + xx[2]*uu[2] + xx[3]*uu[3];
  float ss = xx[0]*vv[0] + xx[1]*vv[1] + xx[2]*vv[2] + xx[3]*vv[3];
  #pragma unroll
  for (int m = 1; m < 64; m <<= 1) { cc += __shfl_xor(cc, m); ss += __shfl_xor(ss, m); }
  if (l == 0) {
    cc += cu[t]; ss += cv[t];
    float r = sqrtf(cc * cc + ss * ss + 1e-8f) - 0.5f;
    resb[t * 256 + b] = sigf(r);
  }
}

// ---------------- persistent recurrent kernel ----------------
__global__ void __launch_bounds__(256, 1)
k_lstm(const float* __restrict__ x, const float* __restrict__ bt1,
       const float* __restrict__ wt2, const float* __restrict__ bt2,
       const float* __restrict__ wg, const float* __restrict__ bg,
       float* __restrict__ out, char* __restrict__ ws) {
  extern __shared__ char sA[];
  const f16* __restrict__ Wcat = (const f16*)(ws + OFF_WCAT);
  const f16* __restrict__ Wt1h = (const f16*)(ws + OFF_WT1);
  f16* A       = (f16*)(ws + OFF_A);
  float* gates = (float*)(ws + OFF_GATES);
  const float* bsum = (const float*)(ws + OFF_BSUM);
  const float* zeta = (const float*)(ws + OFF_ZETA);
  const float* resb = (const float*)(ws + OFF_RES);
  float* tens  = (float*)(ws + OFF_TENS);
  unsigned* bar_arr  = (unsigned*)(ws + OFF_BAR);
  unsigned* bar_flag = bar_arr + NBLK * 32;

  const int tid = threadIdx.x;
  const int w = tid >> 6, l = tid & 63;
  const int bid = blockIdx.x;
  const bool isT1 = (bid >= NGATE);

  int m0, n0, NI, NK, k0, wstr, rowB, bpr;
  const f16* W;
  if (!isT1) { m0 = (bid >> 5) * 64; n0 = (bid & 31) * 64; NI = 24; NK = 24; k0 = 0;   wstr = 768;  bpr = 96;  W = Wcat; }
  else { int j = bid - NGATE; m0 = (j >> 3) * 64; n0 = (j & 7) * 64; NI = 32; NK = 32; k0 = 256; wstr = 1024; bpr = 128; W = Wt1h; }
  rowB = bpr * 16;

  // ---- persistent weight fragments in registers (per wave: 16 output cols, full K) ----
  f16x8 wb[32];
  {
    int row = n0 + w * 16 + (l & 15);
    const f16* Wr = W + (size_t)row * wstr + (l >> 4) * 8;
    #pragma unroll
    for (int ks = 0; ks < 32; ++ks)
      if (ks < NK) wb[ks] = *(const f16x8*)(Wr + ks * 32);
  }

  // ---- phase-2 constants & register state (gates blocks) ----
  const int e0 = (bid * 256 + tid) * 4;
  const int b2 = e0 >> 9, j2 = e0 & 511;
  f32x4 bsi = {0,0,0,0}, bsf = {0,0,0,0}, bsg = {0,0,0,0}, bso = {0,0,0,0};
  if (!isT1) {
    bsi = *(const f32x4*)(bsum + j2);
    bsf = *(const f32x4*)(bsum + 512 + j2);
    bsg = *(const f32x4*)(bsum + 1024 + j2);
    bso = *(const f32x4*)(bsum + 1536 + j2);
  }
  const float wg0 = wg[0], wg1 = wg[1], bt2v = bt2[0], bgv = bg[0];
  float cst[4] = {0,0,0,0}, hst[4] = {0,0,0,0};
  float hh[5][4];
  #pragma unroll
  for (int s = 0; s < 5; ++s) { hh[s][0]=0.f; hh[s][1]=0.f; hh[s][2]=0.f; hh[s][3]=0.f; }

  float w2a = 0.f, b1a = 0.f;
  if (isT1) { int col = n0 + w * 16 + (l & 15); w2a = wt2[col]; b1a = bt1[col]; }

  // ---- staging addressing (matches HW linear LDS write: block B = i*256+tid) ----
  // dest LDS 16B-block B -> (row = B/bpr, c = B%bpr); source block = c ^ (row&7)
  const int srow0 = tid / bpr;
  const int sc0v  = tid - srow0 * bpr;
  const int cstep = 256 - 2 * bpr;          // 64 (gates) or 0 (t1)
  const f16* Abase = A + (size_t)m0 * 1280 + k0;

  unsigned epoch = 0;

  for (int t = 0; t < 512; ++t) {
    // ========== phase 1: stage A tile (all loads in flight at once) ==========
    {
      int row = srow0, c = sc0v;
      #pragma unroll
      for (int i = 0; i < 32; ++i)
        if (i < NI) {
          int csrc = c ^ (row & 7);
          gl_lds16(Abase + (size_t)row * 1280 + csrc * 8, sA + i * 4096 + w * 1024);
          c += cstep; row += 2;
          if (c >= bpr) { c -= bpr; row += 1; }
        }
    }
    __syncthreads();

    // ========== MFMA: 64 rows x 16 cols per wave, weights from registers ==========
    f32x4 acc0 = {0,0,0,0}, acc1 = {0,0,0,0}, acc2 = {0,0,0,0}, acc3 = {0,0,0,0};
    {
      const int r0 = l & 15;
      const int kq = l >> 4;
      const int lswz = r0 & 7;
      #pragma unroll
      for (int ks = 0; ks < 32; ++ks)
        if (ks < NK) {
          int cc = ((ks * 4 + kq) ^ lswz) << 4;
          f16x8 a0 = *(const f16x8*)(sA + (r0     ) * rowB + cc);
          f16x8 a1 = *(const f16x8*)(sA + (r0 + 16) * rowB + cc);
          f16x8 a2 = *(const f16x8*)(sA + (r0 + 32) * rowB + cc);
          f16x8 a3 = *(const f16x8*)(sA + (r0 + 48) * rowB + cc);
          acc0 = __builtin_amdgcn_mfma_f32_16x16x32_f16(a0, wb[ks], acc0, 0, 0, 0);
          acc1 = __builtin_amdgcn_mfma_f32_16x16x32_f16(a1, wb[ks], acc1, 0, 0, 0);
          acc2 = __builtin_amdgcn_mfma_f32_16x16x32_f16(a2, wb[ks], acc2, 0, 0, 0);
          acc3 = __builtin_amdgcn_mfma_f32_16x16x32_f16(a3, wb[ks], acc3, 0, 0, 0);
        }
    }

    if (!isT1) {
      int gr = m0 + ((l >> 4) << 2);
      int gc = n0 + w * 16 + (l & 15);
      float* gp = gates + (size_t)gr * 2048 + gc;
      #pragma unroll
      for (int r = 0; r < 4; ++r) {
        gp[(r     ) * 2048] = acc0[r];
        gp[(r + 16) * 2048] = acc1[r];
        gp[(r + 32) * 2048] = acc2[r];
        gp[(r + 48) * 2048] = acc3[r];
      }
    } else {
      float* tb = tens + (t & 1) * 256;
      #pragma unroll
      for (int mi = 0; mi < 4; ++mi) {
        f32x4 av = (mi == 0) ? acc0 : (mi == 1) ? acc1 : (mi == 2) ? acc2 : acc3;
        float sr[4];
        #pragma unroll
        for (int r = 0; r < 4; ++r) sr[r] = fmaxf(av[r] + b1a, 0.f) * w2a;
        #pragma unroll
        for (int m = 1; m < 16; m <<= 1) {
          #pragma unroll
          for (int r = 0; r < 4; ++r) sr[r] += __shfl_xor(sr[r], m);
        }
        if ((l & 15) == 0) {
          int brow = m0 + mi * 16 + ((l >> 4) << 2);
          #pragma unroll
          for (int r = 0; r < 4; ++r) atomicAdd(&tb[brow + r], sr[r]);
        }
      }
    }

    ++epoch; gbar(bar_arr, bar_flag, epoch);

    // ========== phase 2 ==========
    if (!isT1) {
      const float zt = zeta[t];
      const float* gp = gates + (size_t)b2 * 2048 + j2;
      f32x4 gi = *(const f32x4*)(gp);
      f32x4 gf = *(const f32x4*)(gp + 512);
      f32x4 gg = *(const f32x4*)(gp + 1024);
      f32x4 go = *(const f32x4*)(gp + 1536);
      float tn = (t < 2) ? 0.f : sigf(tens[(t & 1) * 256 + b2] + bt2v);
      float rs = resb[t * 256 + b2];
      float gate = sigf(wg0 * rs + wg1 * tn + bgv);
      float ho[4], cn[4], hsum[4];
      #pragma unroll
      for (int r = 0; r < 4; ++r) {
        float ci = sigf(gi[r] + bsi[r]);
        float cf = sigf(gf[r] + bsf[r]);
        float cg = tanh_(gg[r] + bsg[r]);
        float co = sigf(go[r] + bso[r]);
        float c_new = cf * cst[r] + ci * cg;
        float h_new = co * tanh_(c_new);
        float hout = h_new + gate * (zt * hst[r]);
        cst[r] = c_new; hst[r] = hout;
        cn[r] = c_new; ho[r] = hout;
        hsum[r] = hh[1][r] + hh[2][r] + hh[3][r] + hh[4][r] + hout;
      }
      #pragma unroll
      for (int s = 0; s < 4; ++s) {
        #pragma unroll
        for (int r = 0; r < 4; ++r) hh[s][r] = hh[s + 1][r];
      }
      #pragma unroll
      for (int r = 0; r < 4; ++r) hh[4][r] = ho[r];
      f16x4 hf, mf;
      #pragma unroll
      for (int r = 0; r < 4; ++r) { hf[r] = (f16)ho[r]; mf[r] = (f16)(hsum[r] * 0.2f); }
      *(f16x4*)(A + b2 * 1280 + 256 + j2) = hf;
      *(f16x4*)(A + b2 * 1280 + 768 + j2) = mf;
      f32x4 hv = {ho[0], ho[1], ho[2], ho[3]};
      *(f32x4*)(out + ((size_t)b2 * 512 + t) * 512 + j2) = hv;
      if (t == 511) {
        f32x4 cv4 = {cn[0], cn[1], cn[2], cn[3]};
        *(f32x4*)(out + 67108864 + e0) = hv;
        *(f32x4*)(out + 67108864 + 131072 + e0) = cv4;
      }
      if (bid == 0) tens[((t + 1) & 1) * 256 + tid] = 0.f;
    } else {
      if (t < 511) {
        int p0 = ((bid - NGATE) * 256 + tid) * 8;
        int pb = p0 >> 8, pk = p0 & 255;
        const float* xp = x + ((size_t)pb * 512 + (t + 1)) * 256 + pk;
        f32x4 xa = *(const f32x4*)xp;
        f32x4 xb = *(const f32x4*)(xp + 4);
        f16x8 xf;
        #pragma unroll
        for (int r = 0; r < 4; ++r) { xf[r] = (f16)xa[r]; xf[4 + r] = (f16)xb[r]; }
        *(f16x8*)(A + pb * 1280 + pk) = xf;
      }
    }

    ++epoch; gbar(bar_arr, bar_flag, epoch);
  }
}

extern "C" void kernel_launch(void* const* d_in, const int* in_sizes, int n_in,
                              void* d_out, int out_size, void* d_ws, size_t ws_size,
                              hipStream_t stream) {
  (void)in_sizes; (void)n_in; (void)out_size; (void)ws_size;
  const float* x     = (const float*)d_in[0];
  const float* Wih   = (const float*)d_in[1];
  const float* Whh   = (const float*)d_in[2];
  const float* bih   = (const float*)d_in[3];
  const float* bhh   = (const float*)d_in[4];
  const float* Wproj = (const float*)d_in[5];
  const float* bproj = (const float*)d_in[6];
  const float* Wt1   = (const float*)d_in[7];
  const float* bt1   = (const float*)d_in[8];
  const float* Wt2   = (const float*)d_in[9];
  const float* bt2   = (const float*)d_in[10];
  const float* Wg    = (const float*)d_in[11];
  const float* bg    = (const float*)d_in[12];
  float* out = (float*)d_out;
  char* ws = (char*)d_ws;
  hipFuncSetAttribute((const void*)k_lstm, hipFuncAttributeMaxDynamicSharedMemorySize, 131072);
  k_init<<<dim3(1024), dim3(256), 0, stream>>>(x, Wih, Whh, bih, bhh, Wt1, ws);
  k_tables<<<dim3(512), dim3(256), 0, stream>>>(Wproj, bproj, ws);
  k_res<<<dim3(32768), dim3(256), 0, stream>>>(x, ws);
  k_lstm<<<dim3(NBLK), dim3(256), 131072, stream>>>(x, bt1, Wt2, bt2, Wg, bg, out, ws);
}

// Round 4
// 11343.419 us; speedup vs baseline: 2.2242x; 2.2242x over previous
//
#include <hip/hip_runtime.h>

typedef _Float16 f16;
typedef _Float16 f16x8 __attribute__((ext_vector_type(8)));
typedef _Float16 f16x4 __attribute__((ext_vector_type(4)));
typedef float f32x4 __attribute__((ext_vector_type(4)));
typedef unsigned long long u64;

#define DEVFN static __device__ __forceinline__

#define NBLK 160
#define NGATE 128
#define GRP 40u   // blocks per panel group (32 gate + 8 t1)

// ---------------- workspace layout (bytes) ----------------
#define OFF_WCAT 0ULL                          // 2048*768*2
#define OFF_WT1  (OFF_WCAT + 2048ULL*768*2)    // 512*1024*2
#define OFF_A0   (OFF_WT1  + 512ULL*1024*2)    // 256*1280*2
#define OFF_A1   (OFF_A0   + 256ULL*1280*2)    // 256*1280*2
#define OFF_GATES (OFF_A1  + 256ULL*1280*2)    // 256*2048*4
#define OFF_BSUM (OFF_GATES + 256ULL*2048*4)   // 2048*4
#define OFF_U    (OFF_BSUM + 2048ULL*4)
#define OFF_V    (OFF_U    + 512ULL*256*4)
#define OFF_CU   (OFF_V    + 512ULL*256*4)
#define OFF_CV   (OFF_CU   + 512ULL*4)
#define OFF_ZETA (OFF_CV   + 512ULL*4)
#define OFF_RES  (OFF_ZETA + 512ULL*4)         // 512*256*4
#define OFF_TENS (OFF_RES  + 512ULL*256*4)     // 2*256*4
#define OFF_CNT  (OFF_TENS + 2ULL*256*4)       // 512*4 (counters, 128B-padded)

__constant__ float CGAM[15] = {14.134725f, 21.02204f, 25.010858f, 30.424876f, 32.935062f,
  37.586178f, 40.91872f, 43.327073f, 48.005151f, 49.773832f, 52.970321f,
  56.446248f, 59.347044f, 60.831779f, 65.112544f};

DEVFN float sigf(float v) { return 1.f / (1.f + __expf(-v)); }
DEVFN float tanh_(float v) {
  v = fminf(fmaxf(v, -15.f), 15.f);
  float e = __expf(2.f * v);
  return (e - 1.f) / (e + 1.f);
}

// ---- fence-free LLC-coherent (sc1) access helpers ----
DEVFN float ald_f32(const float* p) {
  unsigned v = __hip_atomic_load((const unsigned*)p, __ATOMIC_RELAXED, __HIP_MEMORY_SCOPE_AGENT);
  union { unsigned u; float f; } c; c.u = v; return c.f;
}
DEVFN void ast_f32(float* p, float v) {
  union { float f; unsigned u; } c; c.f = v;
  __hip_atomic_store((unsigned*)p, c.u, __ATOMIC_RELAXED, __HIP_MEMORY_SCOPE_AGENT);
}
DEVFN u64 ald_u64(const void* p) {
  return __hip_atomic_load((const u64*)p, __ATOMIC_RELAXED, __HIP_MEMORY_SCOPE_AGENT);
}
DEVFN void ast_u64(void* p, u64 v) {
  __hip_atomic_store((u64*)p, v, __ATOMIC_RELAXED, __HIP_MEMORY_SCOPE_AGENT);
}
DEVFN float loF(u64 q) { union { unsigned u; float f; } c; c.u = (unsigned)q; return c.f; }
DEVFN float hiF(u64 q) { union { unsigned u; float f; } c; c.u = (unsigned)(q >> 32); return c.f; }

// producer: drain own vmem, block-converge, one relaxed bump
DEVFN void bump(unsigned* p) {
  asm volatile("s_waitcnt vmcnt(0)" ::: "memory");
  __syncthreads();
  if (threadIdx.x == 0)
    __hip_atomic_fetch_add(p, 1u, __ATOMIC_RELAXED, __HIP_MEMORY_SCOPE_AGENT);
}
// consumer: one thread polls relaxed, block-converge
DEVFN void wait_ge(unsigned* p, unsigned target) {
  if (threadIdx.x == 0) {
    long sp = 0;
    while (__hip_atomic_load(p, __ATOMIC_RELAXED, __HIP_MEMORY_SCOPE_AGENT) < target) {
      __builtin_amdgcn_s_sleep(1);
      if (++sp > (1L << 22)) break;
    }
  }
  __syncthreads();
}

// ---------------- init ----------------
__global__ void k_init(const float* __restrict__ x, const float* __restrict__ Wih,
                       const float* __restrict__ Whh, const float* __restrict__ bih,
                       const float* __restrict__ bhh, const float* __restrict__ Wt1f,
                       char* __restrict__ ws) {
  f16* Wcat = (f16*)(ws + OFF_WCAT);
  f16* Wt1h = (f16*)(ws + OFF_WT1);
  f16* A0   = (f16*)(ws + OFF_A0);
  float* bsum = (float*)(ws + OFF_BSUM);
  float* tens = (float*)(ws + OFF_TENS);
  unsigned* cnt = (unsigned*)(ws + OFF_CNT);
  int gtid = blockIdx.x * blockDim.x + threadIdx.x;
  int nth = gridDim.x * blockDim.x;
  for (int i = gtid; i < 2048 * 768; i += nth) {
    int n = i / 768, k = i - n * 768;
    float w = (k < 256) ? Wih[n * 256 + k] : Whh[n * 512 + (k - 256)];
    Wcat[i] = (f16)w;
  }
  for (int i = gtid; i < 512 * 1024; i += nth) Wt1h[i] = (f16)Wt1f[i];
  for (int i = gtid; i < 2048; i += nth) bsum[i] = bih[i] + bhh[i];
  for (int i = gtid; i < 256 * 1280; i += nth) {
    int b = i / 1280, k = i - b * 1280;
    A0[i] = (k < 256) ? (f16)x[(size_t)b * 131072 + k] : (f16)0.f;
  }
  for (int i = gtid; i < 512; i += nth) tens[i] = 0.f;
  for (int i = gtid; i < 512; i += nth) cnt[i] = 0u;
}

// ---------------- per-t tables ----------------
__global__ void k_tables(const float* __restrict__ Wproj, const float* __restrict__ bproj,
                         char* __restrict__ ws) {
  float* u    = (float*)(ws + OFF_U);
  float* v    = (float*)(ws + OFF_V);
  float* cu   = (float*)(ws + OFF_CU);
  float* cv   = (float*)(ws + OFF_CV);
  float* zeta = (float*)(ws + OFF_ZETA);
  int t = blockIdx.x;
  int k = threadIdx.x;
  float tf = (float)t;
  float cg[15], sg[15], ph[15];
  #pragma unroll
  for (int m = 0; m < 15; ++m) {
    float ang = CGAM[m] * tf;
    cg[m] = cosf(ang);
    sg[m] = sinf(ang);
    ph[m] = (float)exp(-0.1 * (double)CGAM[m]);
  }
  float uu = 0.f, vv = 0.f;
  #pragma unroll
  for (int m = 0; m < 15; ++m) {
    uu += Wproj[m * 256 + k] * cg[m] * ph[m];
    vv += Wproj[(15 + m) * 256 + k] * sg[m] * ph[m];
  }
  u[t * 256 + k] = uu;
  v[t * 256 + k] = vv;
  if (k == 0) {
    float a = 0.f, b2 = 0.f, z = 0.f;
    #pragma unroll
    for (int m = 0; m < 15; ++m) {
      a  += bproj[m] * cg[m] * ph[m];
      b2 += bproj[15 + m] * sg[m] * ph[m];
      z  += ph[m] * cg[m];
    }
    cu[t] = a; cv[t] = b2; zeta[t] = z / 15.f;
  }
}

// ---------------- resonance precompute ----------------
__global__ void k_res(const float* __restrict__ x, char* __restrict__ ws) {
  const float* u  = (const float*)(ws + OFF_U);
  const float* v  = (const float*)(ws + OFF_V);
  const float* cu = (const float*)(ws + OFF_CU);
  const float* cv = (const float*)(ws + OFF_CV);
  float* resb     = (float*)(ws + OFF_RES);
  int wid = blockIdx.x * 4 + (threadIdx.x >> 6);
  int l = threadIdx.x & 63;
  int b = wid >> 9, t = wid & 511;
  const f32x4 xx = *(const f32x4*)(x + ((size_t)(b * 512 + t)) * 256 + l * 4);
  const f32x4 uu = *(const f32x4*)(u + t * 256 + l * 4);
  const f32x4 vv = *(const f32x4*)(v + t * 256 + l * 4);
  float cc = xx[0]*uu[0] + xx[1]*uu[1] + xx[2]*uu[2] + xx[3]*uu[3];
  float ss = xx[0]*vv[0] + xx[1]*vv[1] + xx[2]*vv[2] + xx[3]*vv[3];
  #pragma unroll
  for (int m = 1; m < 64; m <<= 1) { cc += __shfl_xor(cc, m); ss += __shfl_xor(ss, m); }
  if (l == 0) {
    cc += cu[t]; ss += cv[t];
    float r = sqrtf(cc * cc + ss * ss + 1e-8f) - 0.5f;
    resb[t * 256 + b] = sigf(r);
  }
}

// ---- staged tile GEMM: atomic(sc1) loads -> swizzled LDS -> MFMA ----
template<int NI, int BPR, int ROWB, int NK>
DEVFN void tile_gemm(const f16* __restrict__ Abase, char* sA, const f16x8* wb,
                     int tid, int l, f32x4& a0, f32x4& a1, f32x4& a2, f32x4& a3) {
  u64 lo[NI], hi[NI];
  {
    int row = tid / BPR, c = tid % BPR;
    #pragma unroll
    for (int i = 0; i < NI; ++i) {
      const u64* p = (const u64*)(Abase + (size_t)row * 1280 + c * 8);
      lo[i] = ald_u64(p);
      hi[i] = ald_u64(p + 1);
      c += 256 - 2 * BPR; row += 2;
      if (c >= BPR) { c -= BPR; ++row; }
    }
  }
  {
    int row = tid / BPR, c = tid % BPR;
    #pragma unroll
    for (int i = 0; i < NI; ++i) {
      union { u64 q[2]; uint4 v; } uq; uq.q[0] = lo[i]; uq.q[1] = hi[i];
      *(uint4*)(sA + row * ROWB + ((c ^ (row & 7)) << 4)) = uq.v;
      c += 256 - 2 * BPR; row += 2;
      if (c >= BPR) { c -= BPR; ++row; }
    }
  }
  __syncthreads();
  const int r0 = l & 15;
  const int kq = l >> 4;
  const int lswz = r0 & 7;
  #pragma unroll
  for (int ks = 0; ks < NK; ++ks) {
    int cc = ((ks * 4 + kq) ^ lswz) << 4;
    f16x8 q0 = *(const f16x8*)(sA + (r0     ) * ROWB + cc);
    f16x8 q1 = *(const f16x8*)(sA + (r0 + 16) * ROWB + cc);
    f16x8 q2 = *(const f16x8*)(sA + (r0 + 32) * ROWB + cc);
    f16x8 q3 = *(const f16x8*)(sA + (r0 + 48) * ROWB + cc);
    a0 = __builtin_amdgcn_mfma_f32_16x16x32_f16(q0, wb[ks], a0, 0, 0, 0);
    a1 = __builtin_amdgcn_mfma_f32_16x16x32_f16(q1, wb[ks], a1, 0, 0, 0);
    a2 = __builtin_amdgcn_mfma_f32_16x16x32_f16(q2, wb[ks], a2, 0, 0, 0);
    a3 = __builtin_amdgcn_mfma_f32_16x16x32_f16(q3, wb[ks], a3, 0, 0, 0);
  }
}

// ---------------- persistent recurrent kernel ----------------
__global__ void __launch_bounds__(256, 1)
k_lstm(const float* __restrict__ x, const float* __restrict__ bt1,
       const float* __restrict__ wt2, const float* __restrict__ bt2,
       const float* __restrict__ wg, const float* __restrict__ bg,
       float* __restrict__ out, char* __restrict__ ws) {
  extern __shared__ char sA[];
  const f16* __restrict__ Wcat = (const f16*)(ws + OFF_WCAT);
  const f16* __restrict__ Wt1h = (const f16*)(ws + OFF_WT1);
  f16* A0      = (f16*)(ws + OFF_A0);
  f16* A1      = (f16*)(ws + OFF_A1);
  float* gates = (float*)(ws + OFF_GATES);
  const float* bsum = (const float*)(ws + OFF_BSUM);
  const float* zeta = (const float*)(ws + OFF_ZETA);
  const float* resb = (const float*)(ws + OFF_RES);
  float* tens  = (float*)(ws + OFF_TENS);
  unsigned* cnt = (unsigned*)(ws + OFF_CNT);

  const int tid = threadIdx.x;
  const int w = tid >> 6, l = tid & 63;
  const int bid = blockIdx.x;
  const bool isT1 = (bid >= NGATE);

  int p, m0, n0, q1i = 0;
  if (!isT1) { p = bid >> 5; m0 = p * 64; n0 = (bid & 31) * 64; }
  else { int j = bid - NGATE; p = j >> 3; m0 = p * 64; n0 = (j & 7) * 64; q1i = j & 7; }
  unsigned* cntA = cnt + p * 64;
  unsigned* cntG = cnt + p * 64 + 32;

  // ---- persistent weight fragments (per wave: 16 output cols, full K) ----
  f16x8 wb[32];
  if (!isT1) {
    int row = n0 + w * 16 + (l & 15);
    const f16* Wr = Wcat + (size_t)row * 768 + (l >> 4) * 8;
    #pragma unroll
    for (int ks = 0; ks < 24; ++ks) wb[ks] = *(const f16x8*)(Wr + ks * 32);
  } else {
    int row = n0 + w * 16 + (l & 15);
    const f16* Wr = Wt1h + (size_t)row * 1024 + (l >> 4) * 8;
    #pragma unroll
    for (int ks = 0; ks < 32; ++ks) wb[ks] = *(const f16x8*)(Wr + ks * 32);
  }

  // ---- phase-2 constants & register state ----
  const int e0 = (bid * 256 + tid) * 4;
  const int b2 = e0 >> 9, j2 = e0 & 511;
  f32x4 bsi = {0,0,0,0}, bsf = {0,0,0,0}, bsg = {0,0,0,0}, bso = {0,0,0,0};
  if (!isT1) {
    bsi = *(const f32x4*)(bsum + j2);
    bsf = *(const f32x4*)(bsum + 512 + j2);
    bsg = *(const f32x4*)(bsum + 1024 + j2);
    bso = *(const f32x4*)(bsum + 1536 + j2);
  }
  const float wg0 = wg[0], wg1 = wg[1], bt2v = bt2[0], bgv = bg[0];
  float cst[4] = {0,0,0,0}, hst[4] = {0,0,0,0};
  float hh[5][4];
  #pragma unroll
  for (int s = 0; s < 5; ++s) { hh[s][0]=0.f; hh[s][1]=0.f; hh[s][2]=0.f; hh[s][3]=0.f; }
  float w2a = 0.f, b1a = 0.f;
  if (isT1) { int col = n0 + w * 16 + (l & 15); w2a = wt2[col]; b1a = bt1[col]; }

  for (int t = 0; t < 512; ++t) {
    const f16* Acur = (t & 1) ? A1 : A0;
    f16* Anext      = (t & 1) ? A0 : A1;

    // ===== phase 1: wait A[t] ready, tile GEMM =====
    wait_ge(cntA, GRP * (unsigned)t);
    if (isT1 && q1i == 0 && tid < 64)
      ast_f32(&tens[((t + 1) & 1) * 256 + m0 + tid], 0.f);   // recycle buffer (readers done)

    f32x4 acc0 = {0,0,0,0}, acc1 = {0,0,0,0}, acc2 = {0,0,0,0}, acc3 = {0,0,0,0};
    if (!isT1)
      tile_gemm<24, 96, 1536, 24>(Acur + (size_t)m0 * 1280, sA, wb, tid, l, acc0, acc1, acc2, acc3);
    else
      tile_gemm<32, 128, 2048, 32>(Acur + (size_t)m0 * 1280 + 256, sA, wb, tid, l, acc0, acc1, acc2, acc3);

    if (!isT1) {
      int gr = m0 + ((l >> 4) << 2);
      int gc = n0 + w * 16 + (l & 15);
      float* gp = gates + (size_t)gr * 2048 + gc;
      #pragma unroll
      for (int r = 0; r < 4; ++r) {
        ast_f32(&gp[(r     ) * 2048], acc0[r]);
        ast_f32(&gp[(r + 16) * 2048], acc1[r]);
        ast_f32(&gp[(r + 32) * 2048], acc2[r]);
        ast_f32(&gp[(r + 48) * 2048], acc3[r]);
      }
    } else {
      float* tb = tens + (t & 1) * 256;
      #pragma unroll
      for (int mi = 0; mi < 4; ++mi) {
        f32x4 av = (mi == 0) ? acc0 : (mi == 1) ? acc1 : (mi == 2) ? acc2 : acc3;
        float sr[4];
        #pragma unroll
        for (int r = 0; r < 4; ++r) sr[r] = fmaxf(av[r] + b1a, 0.f) * w2a;
        #pragma unroll
        for (int m = 1; m < 16; m <<= 1) {
          #pragma unroll
          for (int r = 0; r < 4; ++r) sr[r] += __shfl_xor(sr[r], m);
        }
        if ((l & 15) == 0) {
          int brow = m0 + mi * 16 + ((l >> 4) << 2);
          #pragma unroll
          for (int r = 0; r < 4; ++r) atomicAdd(&tb[brow + r], sr[r]);
        }
      }
    }
    bump(cntG);

    // ===== phase 2 =====
    if (!isT1) {
      wait_ge(cntG, GRP * (unsigned)(t + 1));
      const float zt = zeta[t];
      const float* gp = gates + (size_t)b2 * 2048 + j2;
      u64 qa = ald_u64(gp),        qb = ald_u64(gp + 2);
      u64 qc = ald_u64(gp + 512),  qd = ald_u64(gp + 514);
      u64 qe = ald_u64(gp + 1024), qf = ald_u64(gp + 1026);
      u64 qg = ald_u64(gp + 1536), qh = ald_u64(gp + 1538);
      float gi[4] = {loF(qa), hiF(qa), loF(qb), hiF(qb)};
      float gf[4] = {loF(qc), hiF(qc), loF(qd), hiF(qd)};
      float gg[4] = {loF(qe), hiF(qe), loF(qf), hiF(qf)};
      float go[4] = {loF(qg), hiF(qg), loF(qh), hiF(qh)};
      float tnraw = ald_f32(&tens[(t & 1) * 256 + b2]);
      float tn = (t < 2) ? 0.f : sigf(tnraw + bt2v);
      float rs = resb[t * 256 + b2];
      float gate = sigf(wg0 * rs + wg1 * tn + bgv);
      float ho[4], cn[4], hs5[4];
      #pragma unroll
      for (int r = 0; r < 4; ++r) {
        float ci = sigf(gi[r] + bsi[r]);
        float cf = sigf(gf[r] + bsf[r]);
        float cg = tanh_(gg[r] + bsg[r]);
        float co = sigf(go[r] + bso[r]);
        float c_new = cf * cst[r] + ci * cg;
        float h_new = co * tanh_(c_new);
        float hout = h_new + gate * (zt * hst[r]);
        cst[r] = c_new; hst[r] = hout;
        cn[r] = c_new; ho[r] = hout;
        hs5[r] = hh[1][r] + hh[2][r] + hh[3][r] + hh[4][r] + hout;
      }
      #pragma unroll
      for (int s = 0; s < 4; ++s) {
        #pragma unroll
        for (int r = 0; r < 4; ++r) hh[s][r] = hh[s + 1][r];
      }
      #pragma unroll
      for (int r = 0; r < 4; ++r) hh[4][r] = ho[r];
      f16x4 hf, mf;
      #pragma unroll
      for (int r = 0; r < 4; ++r) { hf[r] = (f16)ho[r]; mf[r] = (f16)(hs5[r] * 0.2f); }
      union { f16x4 f; u64 q; } uh, um; uh.f = hf; um.f = mf;
      ast_u64(Anext + b2 * 1280 + 256 + j2, uh.q);
      ast_u64(Anext + b2 * 1280 + 768 + j2, um.q);
      f32x4 hv = {ho[0], ho[1], ho[2], ho[3]};
      *(f32x4*)(out + ((size_t)b2 * 512 + t) * 512 + j2) = hv;
      if (t == 511) {
        f32x4 cv4 = {cn[0], cn[1], cn[2], cn[3]};
        *(f32x4*)(out + 67108864 + e0) = hv;
        *(f32x4*)(out + 67108864 + 131072 + e0) = cv4;
      }
    } else {
      if (t < 511) {
        int e = (q1i * 256 + tid) * 8;
        int pb = m0 + (e >> 8), pk = e & 255;
        const float* xp = x + ((size_t)pb * 512 + (t + 1)) * 256 + pk;
        f32x4 xa = *(const f32x4*)xp;
        f32x4 xb = *(const f32x4*)(xp + 4);
        f16x8 xf;
        #pragma unroll
        for (int r = 0; r < 4; ++r) { xf[r] = (f16)xa[r]; xf[4 + r] = (f16)xb[r]; }
        union { f16x8 f; u64 q[2]; } ux; ux.f = xf;
        ast_u64(Anext + pb * 1280 + pk, ux.q[0]);
        ast_u64(Anext + pb * 1280 + pk + 4, ux.q[1]);
      }
    }
    bump(cntA);
  }
}

extern "C" void kernel_launch(void* const* d_in, const int* in_sizes, int n_in,
                              void* d_out, int out_size, void* d_ws, size_t ws_size,
                              hipStream_t stream) {
  (void)in_sizes; (void)n_in; (void)out_size; (void)ws_size;
  const float* x     = (const float*)d_in[0];
  const float* Wih   = (const float*)d_in[1];
  const float* Whh   = (const float*)d_in[2];
  const float* bih   = (const float*)d_in[3];
  const float* bhh   = (const float*)d_in[4];
  const float* Wproj = (const float*)d_in[5];
  const float* bproj = (const float*)d_in[6];
  const float* Wt1   = (const float*)d_in[7];
  const float* bt1   = (const float*)d_in[8];
  const float* Wt2   = (const float*)d_in[9];
  const float* bt2   = (const float*)d_in[10];
  const float* Wg    = (const float*)d_in[11];
  const float* bg    = (const float*)d_in[12];
  float* out = (float*)d_out;
  char* ws = (char*)d_ws;
  hipFuncSetAttribute((const void*)k_lstm, hipFuncAttributeMaxDynamicSharedMemorySize, 131072);
  k_init<<<dim3(1024), dim3(256), 0, stream>>>(x, Wih, Whh, bih, bhh, Wt1, ws);
  k_tables<<<dim3(512), dim3(256), 0, stream>>>(Wproj, bproj, ws);
  k_res<<<dim3(32768), dim3(256), 0, stream>>>(x, ws);
  k_lstm<<<dim3(NBLK), dim3(256), 131072, stream>>>(x, bt1, Wt2, bt2, Wg, bg, out, ws);
}

// Round 5
// 6355.268 us; speedup vs baseline: 3.9699x; 1.7849x over previous
//
#include <hip/hip_runtime.h>

typedef _Float16 f16;
typedef _Float16 f16x8 __attribute__((ext_vector_type(8)));
typedef _Float16 f16x4 __attribute__((ext_vector_type(4)));
typedef float f32x4 __attribute__((ext_vector_type(4)));
typedef unsigned long long u64;

#define DEVFN static __device__ __forceinline__

#define NBLK 160
#define NGATE 128

// ---------------- workspace layout (bytes) ----------------
#define OFF_WCAT 0ULL                          // 2048*768*2
#define OFF_WT1  (OFF_WCAT + 2048ULL*768*2)    // 512*1024*2
#define OFF_A0   (OFF_WT1  + 512ULL*1024*2)    // 256*1280*2
#define OFF_A1   (OFF_A0   + 256ULL*1280*2)    // 256*1280*2
#define OFF_BSUM (OFF_A1   + 256ULL*1280*2)    // 2048*4
#define OFF_U    (OFF_BSUM + 2048ULL*4)
#define OFF_V    (OFF_U    + 512ULL*256*4)
#define OFF_CU   (OFF_V    + 512ULL*256*4)
#define OFF_CV   (OFF_CU   + 512ULL*4)
#define OFF_ZETA (OFF_CV   + 512ULL*4)
#define OFF_RES  (OFF_ZETA + 512ULL*4)         // 512*256*4
#define OFF_TENS (OFF_RES  + 512ULL*256*4)     // 2*256*4
#define OFF_SLOT (OFF_TENS + 2ULL*256*4)       // 4 panels * 64 slots * 128B

__constant__ float CGAM[15] = {14.134725f, 21.02204f, 25.010858f, 30.424876f, 32.935062f,
  37.586178f, 40.91872f, 43.327073f, 48.005151f, 49.773832f, 52.970321f,
  56.446248f, 59.347044f, 60.831779f, 65.112544f};

DEVFN float sigf(float v) { return 1.f / (1.f + __expf(-v)); }
DEVFN float tanh_(float v) {
  v = fminf(fmaxf(v, -15.f), 15.f);
  float e = __expf(2.f * v);
  return (e - 1.f) / (e + 1.f);
}

// ---- fence-free LLC-coherent access helpers ----
DEVFN float ald_f32(const float* p) {
  unsigned v = __hip_atomic_load((const unsigned*)p, __ATOMIC_RELAXED, __HIP_MEMORY_SCOPE_AGENT);
  union { unsigned u; float f; } c; c.u = v; return c.f;
}
DEVFN void ast_f32(float* p, float v) {
  union { float f; unsigned u; } c; c.f = v;
  __hip_atomic_store((unsigned*)p, c.u, __ATOMIC_RELAXED, __HIP_MEMORY_SCOPE_AGENT);
}
DEVFN u64 ald_u64(const void* p) {
  return __hip_atomic_load((const u64*)p, __ATOMIC_RELAXED, __HIP_MEMORY_SCOPE_AGENT);
}
DEVFN void ast_u64(void* p, u64 v) {
  __hip_atomic_store((u64*)p, v, __ATOMIC_RELAXED, __HIP_MEMORY_SCOPE_AGENT);
}

// producer: all waves drain own vmem, converge, one relaxed slot store (NO RMW)
DEVFN void post(unsigned* slot, unsigned v) {
  asm volatile("s_waitcnt vmcnt(0)" ::: "memory");
  __syncthreads();
  if (threadIdx.x == 0)
    __hip_atomic_store(slot, v, __ATOMIC_RELAXED, __HIP_MEMORY_SCOPE_AGENT);
}
// consumer: wave0 gathers n slots (one lane each), exits when all >= target
DEVFN void wait_slots(const unsigned* base, int n, unsigned target) {
  if (threadIdx.x < 64) {
    const unsigned* pp = base + (threadIdx.x < n ? threadIdx.x : 0) * 32;
    const bool mine = threadIdx.x < n;
    long sp = 0;
    for (;;) {
      unsigned v = __hip_atomic_load(pp, __ATOMIC_RELAXED, __HIP_MEMORY_SCOPE_AGENT);
      bool ok = (!mine) || (v >= target);
      if (__all(ok)) break;
      __builtin_amdgcn_s_sleep(1);
      if (++sp > (1L << 24)) break;
    }
  }
  __syncthreads();
}

// ---------------- init ----------------
__global__ void k_init(const float* __restrict__ x, const float* __restrict__ Wih,
                       const float* __restrict__ Whh, const float* __restrict__ bih,
                       const float* __restrict__ bhh, const float* __restrict__ Wt1f,
                       char* __restrict__ ws) {
  f16* Wcat = (f16*)(ws + OFF_WCAT);
  f16* Wt1h = (f16*)(ws + OFF_WT1);
  f16* A0   = (f16*)(ws + OFF_A0);
  float* bsum = (float*)(ws + OFF_BSUM);
  float* tens = (float*)(ws + OFF_TENS);
  unsigned* slots = (unsigned*)(ws + OFF_SLOT);
  int gtid = blockIdx.x * blockDim.x + threadIdx.x;
  int nth = gridDim.x * blockDim.x;
  for (int i = gtid; i < 2048 * 768; i += nth) {
    int n = i / 768, k = i - n * 768;
    float w = (k < 256) ? Wih[n * 256 + k] : Whh[n * 512 + (k - 256)];
    Wcat[i] = (f16)w;
  }
  for (int i = gtid; i < 512 * 1024; i += nth) Wt1h[i] = (f16)Wt1f[i];
  for (int i = gtid; i < 2048; i += nth) bsum[i] = bih[i] + bhh[i];
  for (int i = gtid; i < 256 * 1280; i += nth) {
    int b = i / 1280, k = i - b * 1280;
    A0[i] = (k < 256) ? (f16)x[(size_t)b * 131072 + k] : (f16)0.f;
  }
  for (int i = gtid; i < 512; i += nth) tens[i] = 0.f;
  for (int i = gtid; i < 4 * 64 * 32; i += nth) slots[i] = 0u;
}

// ---------------- per-t tables ----------------
__global__ void k_tables(const float* __restrict__ Wproj, const float* __restrict__ bproj,
                         char* __restrict__ ws) {
  float* u    = (float*)(ws + OFF_U);
  float* v    = (float*)(ws + OFF_V);
  float* cu   = (float*)(ws + OFF_CU);
  float* cv   = (float*)(ws + OFF_CV);
  float* zeta = (float*)(ws + OFF_ZETA);
  int t = blockIdx.x;
  int k = threadIdx.x;
  float tf = (float)t;
  float cg[15], sg[15], ph[15];
  #pragma unroll
  for (int m = 0; m < 15; ++m) {
    float ang = CGAM[m] * tf;
    cg[m] = cosf(ang);
    sg[m] = sinf(ang);
    ph[m] = (float)exp(-0.1 * (double)CGAM[m]);
  }
  float uu = 0.f, vv = 0.f;
  #pragma unroll
  for (int m = 0; m < 15; ++m) {
    uu += Wproj[m * 256 + k] * cg[m] * ph[m];
    vv += Wproj[(15 + m) * 256 + k] * sg[m] * ph[m];
  }
  u[t * 256 + k] = uu;
  v[t * 256 + k] = vv;
  if (k == 0) {
    float a = 0.f, b2 = 0.f, z = 0.f;
    #pragma unroll
    for (int m = 0; m < 15; ++m) {
      a  += bproj[m] * cg[m] * ph[m];
      b2 += bproj[15 + m] * sg[m] * ph[m];
      z  += ph[m] * cg[m];
    }
    cu[t] = a; cv[t] = b2; zeta[t] = z / 15.f;
  }
}

// ---------------- resonance precompute ----------------
__global__ void k_res(const float* __restrict__ x, char* __restrict__ ws) {
  const float* u  = (const float*)(ws + OFF_U);
  const float* v  = (const float*)(ws + OFF_V);
  const float* cu = (const float*)(ws + OFF_CU);
  const float* cv = (const float*)(ws + OFF_CV);
  float* resb     = (float*)(ws + OFF_RES);
  int wid = blockIdx.x * 4 + (threadIdx.x >> 6);
  int l = threadIdx.x & 63;
  int b = wid >> 9, t = wid & 511;
  const f32x4 xx = *(const f32x4*)(x + ((size_t)(b * 512 + t)) * 256 + l * 4);
  const f32x4 uu = *(const f32x4*)(u + t * 256 + l * 4);
  const f32x4 vv = *(const f32x4*)(v + t * 256 + l * 4);
  float cc = xx[0]*uu[0] + xx[1]*uu[1] + xx[2]*uu[2] + xx[3]*uu[3];
  float ss = xx[0]*vv[0] + xx[1]*vv[1] + xx[2]*vv[2] + xx[3]*vv[3];
  #pragma unroll
  for (int m = 1; m < 64; m <<= 1) { cc += __shfl_xor(cc, m); ss += __shfl_xor(ss, m); }
  if (l == 0) {
    cc += cu[t]; ss += cv[t];
    float r = sqrtf(cc * cc + ss * ss + 1e-8f) - 0.5f;
    resb[t * 256 + b] = sigf(r);
  }
}

// ---- staged tile GEMM: 2-pass sc1 loads -> swizzled LDS -> MFMA ----
template<int NI, int BPR, int ROWB, int NK>
DEVFN void tile_gemm(const f16* __restrict__ Abase, char* sA, const f16x8* wb,
                     int tid, int l, f32x4& a0, f32x4& a1, f32x4& a2, f32x4& a3) {
  constexpr int H = NI / 2;
  #pragma unroll
  for (int pass = 0; pass < 2; ++pass) {
    int L = tid + pass * H * 256;
    int row0 = L / BPR, c0v = L - row0 * BPR;
    u64 lo[H], hi[H];
    {
      int row = row0, c = c0v;
      #pragma unroll
      for (int i = 0; i < H; ++i) {
        const u64* p = (const u64*)(Abase + (size_t)row * 1280 + c * 8);
        lo[i] = ald_u64(p);
        hi[i] = ald_u64(p + 1);
        c += 256 - 2 * BPR; row += 2;
        if (c >= BPR) { c -= BPR; ++row; }
      }
    }
    {
      int row = row0, c = c0v;
      #pragma unroll
      for (int i = 0; i < H; ++i) {
        union { u64 q[2]; uint4 v; } uq; uq.q[0] = lo[i]; uq.q[1] = hi[i];
        *(uint4*)(sA + row * ROWB + ((c ^ (row & 7)) << 4)) = uq.v;
        c += 256 - 2 * BPR; row += 2;
        if (c >= BPR) { c -= BPR; ++row; }
      }
    }
  }
  __syncthreads();
  const int r0 = l & 15;
  const int kq = l >> 4;
  const int lswz = r0 & 7;
  #pragma unroll
  for (int ks = 0; ks < NK; ++ks) {
    int cc = ((ks * 4 + kq) ^ lswz) << 4;
    f16x8 q0 = *(const f16x8*)(sA + (r0     ) * ROWB + cc);
    f16x8 q1 = *(const f16x8*)(sA + (r0 + 16) * ROWB + cc);
    f16x8 q2 = *(const f16x8*)(sA + (r0 + 32) * ROWB + cc);
    f16x8 q3 = *(const f16x8*)(sA + (r0 + 48) * ROWB + cc);
    a0 = __builtin_amdgcn_mfma_f32_16x16x32_f16(q0, wb[ks], a0, 0, 0, 0);
    a1 = __builtin_amdgcn_mfma_f32_16x16x32_f16(q1, wb[ks], a1, 0, 0, 0);
    a2 = __builtin_amdgcn_mfma_f32_16x16x32_f16(q2, wb[ks], a2, 0, 0, 0);
    a3 = __builtin_amdgcn_mfma_f32_16x16x32_f16(q3, wb[ks], a3, 0, 0, 0);
  }
}

// ---------------- persistent recurrent kernel ----------------
__global__ void __launch_bounds__(256, 1)
k_lstm(const float* __restrict__ x, const float* __restrict__ bt1,
       const float* __restrict__ wt2, const float* __restrict__ bt2,
       const float* __restrict__ wg, const float* __restrict__ bg,
       float* __restrict__ out, char* __restrict__ ws) {
  extern __shared__ char sA[];
  const f16* __restrict__ Wcat = (const f16*)(ws + OFF_WCAT);
  const f16* __restrict__ Wt1h = (const f16*)(ws + OFF_WT1);
  f16* A0      = (f16*)(ws + OFF_A0);
  f16* A1      = (f16*)(ws + OFF_A1);
  const float* bsum = (const float*)(ws + OFF_BSUM);
  const float* zeta = (const float*)(ws + OFF_ZETA);
  const float* resb = (const float*)(ws + OFF_RES);
  float* tens  = (float*)(ws + OFF_TENS);
  unsigned* slots = (unsigned*)(ws + OFF_SLOT);

  const int tid = threadIdx.x;
  const int w = tid >> 6, l = tid & 63;
  const int bid = blockIdx.x;
  const bool isT1 = (bid >= NGATE);

  int p, c0 = 0, n0 = 0, q1i = 0;
  if (!isT1) { p = bid >> 5; c0 = (bid & 31) * 16; }
  else { int j = bid - NGATE; p = j >> 3; n0 = (j & 7) * 64; q1i = j & 7; }
  const int m0 = p * 64;
  unsigned* slotbase = slots + p * 64 * 32;
  unsigned* arrslot  = slotbase + ((isT1 ? 32 + q1i : (bid & 31)) * 32);
  unsigned* t1base   = slotbase + 40 * 32;

  // ---- persistent weight fragments ----
  f16x8 wb[32];
  if (!isT1) {
    // wave w owns gate type w, columns c0..c0+15, K=768
    int row = w * 512 + c0 + (l & 15);
    const f16* Wr = Wcat + (size_t)row * 768 + (l >> 4) * 8;
    #pragma unroll
    for (int ks = 0; ks < 24; ++ks) wb[ks] = *(const f16x8*)(Wr + ks * 32);
  } else {
    int row = n0 + w * 16 + (l & 15);
    const f16* Wr = Wt1h + (size_t)row * 1024 + (l >> 4) * 8;
    #pragma unroll
    for (int ks = 0; ks < 32; ++ks) wb[ks] = *(const f16x8*)(Wr + ks * 32);
  }

  // ---- per-thread LSTM state: batch b = tid>>2, cols c0 + (tid&3)*4 .. +3 ----
  const int bloc = tid >> 2;
  const int j0 = (tid & 3) * 4;
  const int pb = m0 + bloc;
  f32x4 bsi = {0,0,0,0}, bsf = {0,0,0,0}, bsg = {0,0,0,0}, bso = {0,0,0,0};
  if (!isT1) {
    bsi = *(const f32x4*)(bsum +        c0 + j0);
    bsf = *(const f32x4*)(bsum +  512 + c0 + j0);
    bsg = *(const f32x4*)(bsum + 1024 + c0 + j0);
    bso = *(const f32x4*)(bsum + 1536 + c0 + j0);
  }
  const float wg0 = wg[0], wg1 = wg[1], bt2v = bt2[0], bgv = bg[0];
  float cst[4] = {0,0,0,0}, hst[4] = {0,0,0,0};
  float hh[5][4];
  #pragma unroll
  for (int s = 0; s < 5; ++s) { hh[s][0]=0.f; hh[s][1]=0.f; hh[s][2]=0.f; hh[s][3]=0.f; }
  float w2a = 0.f, b1a = 0.f;
  if (isT1) { int col = n0 + w * 16 + (l & 15); w2a = wt2[col]; b1a = bt1[col]; }

  for (int t = 0; t < 512; ++t) {
    const f16* Acur = (t & 1) ? A1 : A0;
    f16* Anext      = (t & 1) ? A0 : A1;

    wait_slots(slotbase, 40, (unsigned)t);   // A[t] panel ready

    if (!isT1) {
      // ===== gate GEMM: M=64 batches x N=64 (4 gates x 16 cols) x K=768 =====
      f32x4 acc0 = {0,0,0,0}, acc1 = {0,0,0,0}, acc2 = {0,0,0,0}, acc3 = {0,0,0,0};
      tile_gemm<24, 96, 1536, 24>(Acur + (size_t)m0 * 1280, sA, wb, tid, l,
                                  acc0, acc1, acc2, acc3);
      __syncthreads();                       // MFMA reads done before exchange overwrite
      float* sX = (float*)sA;                // [4][64][20] f32 exchange
      {
        const int colw = l & 15;
        const int rb = (l >> 4) * 4;
        #pragma unroll
        for (int m = 0; m < 4; ++m) {
          f32x4 av = (m == 0) ? acc0 : (m == 1) ? acc1 : (m == 2) ? acc2 : acc3;
          #pragma unroll
          for (int r = 0; r < 4; ++r)
            sX[(w * 64 + m * 16 + rb + r) * 20 + colw] = av[r];
        }
      }
      __syncthreads();
      f32x4 gi = *(const f32x4*)&sX[(0 * 64 + bloc) * 20 + j0];
      f32x4 gf = *(const f32x4*)&sX[(1 * 64 + bloc) * 20 + j0];
      f32x4 gg = *(const f32x4*)&sX[(2 * 64 + bloc) * 20 + j0];
      f32x4 go = *(const f32x4*)&sX[(3 * 64 + bloc) * 20 + j0];
      float cn[4], hn[4], hold[4];
      #pragma unroll
      for (int r = 0; r < 4; ++r) {
        float ci = sigf(gi[r] + bsi[r]);
        float cf = sigf(gf[r] + bsf[r]);
        float cgv = tanh_(gg[r] + bsg[r]);
        float co = sigf(go[r] + bso[r]);
        float c_new = cf * cst[r] + ci * cgv;
        hold[r] = hst[r];
        cst[r] = c_new; cn[r] = c_new;
        hn[r] = co * tanh_(c_new);
      }
      // tension ready for this step?
      wait_slots(t1base, 8, (unsigned)(t + 1));
      float tnraw = ald_f32(&tens[(t & 1) * 256 + pb]);
      float tn = (t < 2) ? 0.f : sigf(tnraw + bt2v);
      float rs = resb[t * 256 + pb];
      float gate = sigf(wg0 * rs + wg1 * tn + bgv);
      const float zt = zeta[t];
      float ho[4], hs5[4];
      #pragma unroll
      for (int r = 0; r < 4; ++r) {
        float hout = hn[r] + gate * (zt * hold[r]);
        hst[r] = hout; ho[r] = hout;
        hs5[r] = hh[1][r] + hh[2][r] + hh[3][r] + hh[4][r] + hout;
      }
      #pragma unroll
      for (int s = 0; s < 4; ++s) {
        #pragma unroll
        for (int r = 0; r < 4; ++r) hh[s][r] = hh[s + 1][r];
      }
      #pragma unroll
      for (int r = 0; r < 4; ++r) hh[4][r] = ho[r];
      f16x4 hf, mf;
      #pragma unroll
      for (int r = 0; r < 4; ++r) { hf[r] = (f16)ho[r]; mf[r] = (f16)(hs5[r] * 0.2f); }
      union { f16x4 f; u64 q; } uh, um; uh.f = hf; um.f = mf;
      ast_u64(Anext + pb * 1280 + 256 + c0 + j0, uh.q);
      ast_u64(Anext + pb * 1280 + 768 + c0 + j0, um.q);
      f32x4 hv = {ho[0], ho[1], ho[2], ho[3]};
      *(f32x4*)(out + ((size_t)pb * 512 + t) * 512 + c0 + j0) = hv;
      if (t == 511) {
        f32x4 cv4 = {cn[0], cn[1], cn[2], cn[3]};
        *(f32x4*)(out + 67108864 + pb * 512 + c0 + j0) = hv;
        *(f32x4*)(out + 67108864 + 131072 + pb * 512 + c0 + j0) = cv4;
      }
      post(arrslot, (unsigned)(t + 1));
    } else {
      // ===== t1 block: tension GEMM K=1024 =====
      if (q1i == 0 && tid < 64)
        ast_f32(&tens[((t + 1) & 1) * 256 + m0 + tid], 0.f);  // readers of that parity are done
      f32x4 acc0 = {0,0,0,0}, acc1 = {0,0,0,0}, acc2 = {0,0,0,0}, acc3 = {0,0,0,0};
      tile_gemm<32, 128, 2048, 32>(Acur + (size_t)m0 * 1280 + 256, sA, wb, tid, l,
                                   acc0, acc1, acc2, acc3);
      float* tb = tens + (t & 1) * 256;
      #pragma unroll
      for (int mi = 0; mi < 4; ++mi) {
        f32x4 av = (mi == 0) ? acc0 : (mi == 1) ? acc1 : (mi == 2) ? acc2 : acc3;
        float sr[4];
        #pragma unroll
        for (int r = 0; r < 4; ++r) sr[r] = fmaxf(av[r] + b1a, 0.f) * w2a;
        #pragma unroll
        for (int m = 1; m < 16; m <<= 1) {
          #pragma unroll
          for (int r = 0; r < 4; ++r) sr[r] += __shfl_xor(sr[r], m);
        }
        if ((l & 15) == 0) {
          int brow = m0 + mi * 16 + ((l >> 4) << 2);
          #pragma unroll
          for (int r = 0; r < 4; ++r) atomicAdd(&tb[brow + r], sr[r]);
        }
      }
      post(t1base + q1i * 32, (unsigned)(t + 1));   // tension partials visible
      if (t < 511) {
        int e = (q1i * 256 + tid) * 8;
        int xb = m0 + (e >> 8), pk = e & 255;
        const float* xp = x + ((size_t)xb * 512 + (t + 1)) * 256 + pk;
        f32x4 xa = *(const f32x4*)xp;
        f32x4 xc = *(const f32x4*)(xp + 4);
        f16x8 xf;
        #pragma unroll
        for (int r = 0; r < 4; ++r) { xf[r] = (f16)xa[r]; xf[4 + r] = (f16)xc[r]; }
        union { f16x8 f; u64 q[2]; } ux; ux.f = xf;
        ast_u64(Anext + xb * 1280 + pk, ux.q[0]);
        ast_u64(Anext + xb * 1280 + pk + 4, ux.q[1]);
      }
      post(arrslot, (unsigned)(t + 1));
    }
  }
}

extern "C" void kernel_launch(void* const* d_in, const int* in_sizes, int n_in,
                              void* d_out, int out_size, void* d_ws, size_t ws_size,
                              hipStream_t stream) {
  (void)in_sizes; (void)n_in; (void)out_size; (void)ws_size;
  const float* x     = (const float*)d_in[0];
  const float* Wih   = (const float*)d_in[1];
  const float* Whh   = (const float*)d_in[2];
  const float* bih   = (const float*)d_in[3];
  const float* bhh   = (const float*)d_in[4];
  const float* Wproj = (const float*)d_in[5];
  const float* bproj = (const float*)d_in[6];
  const float* Wt1   = (const float*)d_in[7];
  const float* bt1   = (const float*)d_in[8];
  const float* Wt2   = (const float*)d_in[9];
  const float* bt2   = (const float*)d_in[10];
  const float* Wg    = (const float*)d_in[11];
  const float* bg    = (const float*)d_in[12];
  float* out = (float*)d_out;
  char* ws = (char*)d_ws;
  hipFuncSetAttribute((const void*)k_lstm, hipFuncAttributeMaxDynamicSharedMemorySize, 131072);
  k_init<<<dim3(1024), dim3(256), 0, stream>>>(x, Wih, Whh, bih, bhh, Wt1, ws);
  k_tables<<<dim3(512), dim3(256), 0, stream>>>(Wproj, bproj, ws);
  k_res<<<dim3(32768), dim3(256), 0, stream>>>(x, ws);
  k_lstm<<<dim3(NBLK), dim3(256), 131072, stream>>>(x, bt1, Wt2, bt2, Wg, bg, out, ws);
}

// Round 6
// 5590.301 us; speedup vs baseline: 4.5131x; 1.1368x over previous
//
#include <hip/hip_runtime.h>

typedef _Float16 f16;
typedef _Float16 f16x8 __attribute__((ext_vector_type(8)));
typedef _Float16 f16x4 __attribute__((ext_vector_type(4)));
typedef float f32x4 __attribute__((ext_vector_type(4)));
typedef unsigned long long u64;

#define DEVFN static __device__ __forceinline__

#define NBLK 160
#define NGATE 128

// ---------------- workspace layout (bytes) ----------------
#define OFF_WCAT 0ULL                          // 2048*768*2  (gates, [n][k] k: 0-255 x, 256-767 h)
#define OFF_WT1A (OFF_WCAT + 2048ULL*768*2)    // 512*512*2   (W1h + W1m/5)
#define OFF_WT1B (OFF_WT1A + 512ULL*512*2)     // 512*512*2   (W1m/5)
#define OFF_A0   (OFF_WT1B + 512ULL*512*2)     // 256*768*2   ([batch][0-255 x | 256-767 h])
#define OFF_A1   (OFF_A0   + 256ULL*768*2)
#define OFF_BSUM (OFF_A1   + 256ULL*768*2)     // 2048*4
#define OFF_U    (OFF_BSUM + 2048ULL*4)
#define OFF_V    (OFF_U    + 512ULL*256*4)
#define OFF_CU   (OFF_V    + 512ULL*256*4)
#define OFF_CV   (OFF_CU   + 512ULL*4)
#define OFF_ZETA (OFF_CV   + 512ULL*4)
#define OFF_RES  (OFF_ZETA + 512ULL*4)         // 512*256*4
#define OFF_TENS (OFF_RES  + 512ULL*256*4)     // 2*256*4
#define OFF_SLOT (OFF_TENS + 2ULL*256*4)       // 4 panels * 64 slots * 128B

__constant__ float CGAM[15] = {14.134725f, 21.02204f, 25.010858f, 30.424876f, 32.935062f,
  37.586178f, 40.91872f, 43.327073f, 48.005151f, 49.773832f, 52.970321f,
  56.446248f, 59.347044f, 60.831779f, 65.112544f};

DEVFN float sigf(float v) { return 1.f / (1.f + __expf(-v)); }
DEVFN float tanh_(float v) {
  v = fminf(fmaxf(v, -15.f), 15.f);
  float e = __expf(2.f * v);
  return (e - 1.f) / (e + 1.f);
}

// ---- fence-free LLC-coherent access helpers ----
DEVFN float ald_f32(const float* p) {
  unsigned v = __hip_atomic_load((const unsigned*)p, __ATOMIC_RELAXED, __HIP_MEMORY_SCOPE_AGENT);
  union { unsigned u; float f; } c; c.u = v; return c.f;
}
DEVFN void ast_f32(float* p, float v) {
  union { float f; unsigned u; } c; c.f = v;
  __hip_atomic_store((unsigned*)p, c.u, __ATOMIC_RELAXED, __HIP_MEMORY_SCOPE_AGENT);
}
DEVFN u64 ald_u64(const void* p) {
  return __hip_atomic_load((const u64*)p, __ATOMIC_RELAXED, __HIP_MEMORY_SCOPE_AGENT);
}
DEVFN void ast_u64(void* p, u64 v) {
  __hip_atomic_store((u64*)p, v, __ATOMIC_RELAXED, __HIP_MEMORY_SCOPE_AGENT);
}

// producer: all waves drain own vmem, converge, one relaxed slot store (NO RMW)
DEVFN void post(unsigned* slot, unsigned v) {
  asm volatile("s_waitcnt vmcnt(0)" ::: "memory");
  __syncthreads();
  if (threadIdx.x == 0)
    __hip_atomic_store(slot, v, __ATOMIC_RELAXED, __HIP_MEMORY_SCOPE_AGENT);
}
// consumer: wave0 gathers n slots (one lane each), exits when all >= target
DEVFN void wait_slots(const unsigned* base, int n, unsigned target) {
  if (threadIdx.x < 64) {
    const unsigned* pp = base + (threadIdx.x < n ? threadIdx.x : 0) * 32;
    const bool mine = threadIdx.x < n;
    long sp = 0;
    for (;;) {
      unsigned v = __hip_atomic_load(pp, __ATOMIC_RELAXED, __HIP_MEMORY_SCOPE_AGENT);
      bool ok = (!mine) || (v >= target);
      if (__all(ok)) break;
      __builtin_amdgcn_s_sleep(1);
      if (++sp > (1L << 24)) break;
    }
  }
  __syncthreads();
}

// ---------------- init ----------------
__global__ void k_init(const float* __restrict__ x, const float* __restrict__ Wih,
                       const float* __restrict__ Whh, const float* __restrict__ bih,
                       const float* __restrict__ bhh, const float* __restrict__ Wt1f,
                       char* __restrict__ ws) {
  f16* Wcat = (f16*)(ws + OFF_WCAT);
  f16* WhmA = (f16*)(ws + OFF_WT1A);
  f16* WmB  = (f16*)(ws + OFF_WT1B);
  f16* A0   = (f16*)(ws + OFF_A0);
  float* bsum = (float*)(ws + OFF_BSUM);
  float* tens = (float*)(ws + OFF_TENS);
  unsigned* slots = (unsigned*)(ws + OFF_SLOT);
  int gtid = blockIdx.x * blockDim.x + threadIdx.x;
  int nth = gridDim.x * blockDim.x;
  for (int i = gtid; i < 2048 * 768; i += nth) {
    int n = i / 768, k = i - n * 768;
    float w = (k < 256) ? Wih[n * 256 + k] : Whh[n * 512 + (k - 256)];
    Wcat[i] = (f16)w;
  }
  for (int i = gtid; i < 512 * 512; i += nth) {
    int n = i >> 9, k = i & 511;
    float wh = Wt1f[n * 1024 + k];
    float wm = Wt1f[n * 1024 + 512 + k] * 0.2f;
    WhmA[i] = (f16)(wh + wm);
    WmB[i]  = (f16)wm;
  }
  for (int i = gtid; i < 2048; i += nth) bsum[i] = bih[i] + bhh[i];
  for (int i = gtid; i < 256 * 768; i += nth) {
    int b = i / 768, k = i - b * 768;
    A0[i] = (k < 256) ? (f16)x[(size_t)b * 131072 + k] : (f16)0.f;
  }
  for (int i = gtid; i < 512; i += nth) tens[i] = 0.f;
  for (int i = gtid; i < 4 * 64 * 32; i += nth) slots[i] = 0u;
}

// ---------------- per-t tables ----------------
__global__ void k_tables(const float* __restrict__ Wproj, const float* __restrict__ bproj,
                         char* __restrict__ ws) {
  float* u    = (float*)(ws + OFF_U);
  float* v    = (float*)(ws + OFF_V);
  float* cu   = (float*)(ws + OFF_CU);
  float* cv   = (float*)(ws + OFF_CV);
  float* zeta = (float*)(ws + OFF_ZETA);
  int t = blockIdx.x;
  int k = threadIdx.x;
  float tf = (float)t;
  float cg[15], sg[15], ph[15];
  #pragma unroll
  for (int m = 0; m < 15; ++m) {
    float ang = CGAM[m] * tf;
    cg[m] = cosf(ang);
    sg[m] = sinf(ang);
    ph[m] = (float)exp(-0.1 * (double)CGAM[m]);
  }
  float uu = 0.f, vv = 0.f;
  #pragma unroll
  for (int m = 0; m < 15; ++m) {
    uu += Wproj[m * 256 + k] * cg[m] * ph[m];
    vv += Wproj[(15 + m) * 256 + k] * sg[m] * ph[m];
  }
  u[t * 256 + k] = uu;
  v[t * 256 + k] = vv;
  if (k == 0) {
    float a = 0.f, b2 = 0.f, z = 0.f;
    #pragma unroll
    for (int m = 0; m < 15; ++m) {
      a  += bproj[m] * cg[m] * ph[m];
      b2 += bproj[15 + m] * sg[m] * ph[m];
      z  += ph[m] * cg[m];
    }
    cu[t] = a; cv[t] = b2; zeta[t] = z / 15.f;
  }
}

// ---------------- resonance precompute ----------------
__global__ void k_res(const float* __restrict__ x, char* __restrict__ ws) {
  const float* u  = (const float*)(ws + OFF_U);
  const float* v  = (const float*)(ws + OFF_V);
  const float* cu = (const float*)(ws + OFF_CU);
  const float* cv = (const float*)(ws + OFF_CV);
  float* resb     = (float*)(ws + OFF_RES);
  int wid = blockIdx.x * 4 + (threadIdx.x >> 6);
  int l = threadIdx.x & 63;
  int b = wid >> 9, t = wid & 511;
  const f32x4 xx = *(const f32x4*)(x + ((size_t)(b * 512 + t)) * 256 + l * 4);
  const f32x4 uu = *(const f32x4*)(u + t * 256 + l * 4);
  const f32x4 vv = *(const f32x4*)(v + t * 256 + l * 4);
  float cc = xx[0]*uu[0] + xx[1]*uu[1] + xx[2]*uu[2] + xx[3]*uu[3];
  float ss = xx[0]*vv[0] + xx[1]*vv[1] + xx[2]*vv[2] + xx[3]*vv[3];
  #pragma unroll
  for (int m = 1; m < 64; m <<= 1) { cc += __shfl_xor(cc, m); ss += __shfl_xor(ss, m); }
  if (l == 0) {
    cc += cu[t]; ss += cv[t];
    float r = sqrtf(cc * cc + ss * ss + 1e-8f) - 0.5f;
    resb[t * 256 + b] = sigf(r);
  }
}

#define MFMA16(qv, wv, av) av = __builtin_amdgcn_mfma_f32_16x16x32_f16(qv, wv, av, 0, 0, 0)

// ---------------- persistent recurrent kernel ----------------
__global__ void __launch_bounds__(256, 1)
k_lstm(const float* __restrict__ x, const float* __restrict__ bt1,
       const float* __restrict__ wt2, const float* __restrict__ bt2,
       const float* __restrict__ wg, const float* __restrict__ bg,
       float* __restrict__ out, char* __restrict__ ws) {
  extern __shared__ char sA[];
  const f16* __restrict__ Wcat = (const f16*)(ws + OFF_WCAT);
  const f16* __restrict__ WhmA = (const f16*)(ws + OFF_WT1A);
  const f16* __restrict__ WmB  = (const f16*)(ws + OFF_WT1B);
  f16* A0      = (f16*)(ws + OFF_A0);
  f16* A1      = (f16*)(ws + OFF_A1);
  const float* bsum = (const float*)(ws + OFF_BSUM);
  const float* zeta = (const float*)(ws + OFF_ZETA);
  const float* resb = (const float*)(ws + OFF_RES);
  float* tens  = (float*)(ws + OFF_TENS);
  unsigned* slots = (unsigned*)(ws + OFF_SLOT);

  const int tid = threadIdx.x;
  const int w = tid >> 6, l = tid & 63;
  const int bid = blockIdx.x;
  const int r0 = l & 15, kq = l >> 4, lswz = r0 & 7;

  char* sH = sA;                       // 64 x 512 f16 = 64 KB (h tile)

  if (bid < NGATE) {
    // ================= GATE BLOCK =================
    const int p = bid >> 5, m0 = p * 64;
    const int c0 = (bid & 31) * 16;
    unsigned* slotbase = slots + p * 64 * 32;
    unsigned* arrslot  = slotbase + (bid & 31) * 32;
    unsigned* t1base   = slotbase + 32 * 32;
    char* sXt = sA + 65536;            // 64 x 256 f16 = 32 KB (x tile)
    float* sX = (float*)(sA + 98304);  // 256 x 20 f32 = 20 KB (exchange)

    // weights: wave w = gate type w, cols c0..c0+15
    f16x8 wbh[16], wbx[8];
    {
      int row = w * 512 + c0 + r0;
      const f16* Wr = Wcat + (size_t)row * 768 + kq * 8;
      #pragma unroll
      for (int ks = 0; ks < 16; ++ks) wbh[ks] = *(const f16x8*)(Wr + 256 + ks * 32);
      #pragma unroll
      for (int ks = 0; ks < 8; ++ks)  wbx[ks] = *(const f16x8*)(Wr + ks * 32);
    }

    const int bloc = tid >> 2;
    const int j0 = (tid & 3) * 4;
    const int pb = m0 + bloc;
    f32x4 bsi = *(const f32x4*)(bsum +        c0 + j0);
    f32x4 bsf = *(const f32x4*)(bsum +  512 + c0 + j0);
    f32x4 bsg = *(const f32x4*)(bsum + 1024 + c0 + j0);
    f32x4 bso = *(const f32x4*)(bsum + 1536 + c0 + j0);
    const float wg0 = wg[0], wg1 = wg[1], bt2v = bt2[0], bgv = bg[0];
    float cst[4] = {0,0,0,0}, hst[4] = {0,0,0,0};

    f32x4 acc0 = {0,0,0,0}, acc1 = {0,0,0,0}, acc2 = {0,0,0,0}, acc3 = {0,0,0,0};

    // ---- pre-loop: stage x_0, PGx into acc ----
    {
      u64 lo[8], hi[8];
      #pragma unroll
      for (int i = 0; i < 8; ++i) {
        const int L = i * 256 + tid;
        const int row = L >> 5, c = L & 31;
        const u64* pp = (const u64*)(A0 + (size_t)(m0 + row) * 768 + c * 8);
        lo[i] = ald_u64(pp); hi[i] = ald_u64(pp + 1);
      }
      #pragma unroll
      for (int i = 0; i < 8; ++i) {
        const int L = i * 256 + tid;
        const int row = L >> 5, c = L & 31;
        union { u64 q[2]; uint4 v4; } uq; uq.q[0] = lo[i]; uq.q[1] = hi[i];
        *(uint4*)(sXt + row * 512 + ((c ^ (row & 7)) << 4)) = uq.v4;
      }
      __syncthreads();
      #pragma unroll
      for (int ks = 0; ks < 8; ++ks) {
        const int cc = ((ks * 4 + kq) ^ lswz) << 4;
        f16x8 q0 = *(const f16x8*)(sXt + (r0     ) * 512 + cc);
        f16x8 q1 = *(const f16x8*)(sXt + (r0 + 16) * 512 + cc);
        f16x8 q2 = *(const f16x8*)(sXt + (r0 + 32) * 512 + cc);
        f16x8 q3 = *(const f16x8*)(sXt + (r0 + 48) * 512 + cc);
        MFMA16(q0, wbx[ks], acc0); MFMA16(q1, wbx[ks], acc1);
        MFMA16(q2, wbx[ks], acc2); MFMA16(q3, wbx[ks], acc3);
      }
    }

    for (int t = 0; t < 512; ++t) {
      const f16* Acur = (t & 1) ? A1 : A0;
      f16* Anext      = (t & 1) ? A0 : A1;

      wait_slots(slotbase, 32, (unsigned)t);       // h_{t-1} ready

      // stage h tile (64KB), single flight
      {
        u64 lo[16], hi[16];
        #pragma unroll
        for (int i = 0; i < 16; ++i) {
          const int L = i * 256 + tid;
          const int row = L >> 6, c = L & 63;
          const u64* pp = (const u64*)(Acur + (size_t)(m0 + row) * 768 + 256 + c * 8);
          lo[i] = ald_u64(pp); hi[i] = ald_u64(pp + 1);
        }
        #pragma unroll
        for (int i = 0; i < 16; ++i) {
          const int L = i * 256 + tid;
          const int row = L >> 6, c = L & 63;
          union { u64 q[2]; uint4 v4; } uq; uq.q[0] = lo[i]; uq.q[1] = hi[i];
          *(uint4*)(sH + row * 1024 + ((c ^ (row & 7)) << 4)) = uq.v4;
        }
      }
      __syncthreads();
      // h-GEMM K=512 accumulating onto PGx
      #pragma unroll
      for (int ks = 0; ks < 16; ++ks) {
        const int cc = ((ks * 4 + kq) ^ lswz) << 4;
        f16x8 q0 = *(const f16x8*)(sH + (r0     ) * 1024 + cc);
        f16x8 q1 = *(const f16x8*)(sH + (r0 + 16) * 1024 + cc);
        f16x8 q2 = *(const f16x8*)(sH + (r0 + 32) * 1024 + cc);
        f16x8 q3 = *(const f16x8*)(sH + (r0 + 48) * 1024 + cc);
        MFMA16(q0, wbh[ks], acc0); MFMA16(q1, wbh[ks], acc1);
        MFMA16(q2, wbh[ks], acc2); MFMA16(q3, wbh[ks], acc3);
      }
      // exchange: acc -> sX -> per-thread gate quads
      {
        const int rb = kq * 4;
        #pragma unroll
        for (int m = 0; m < 4; ++m) {
          f32x4 av = (m == 0) ? acc0 : (m == 1) ? acc1 : (m == 2) ? acc2 : acc3;
          #pragma unroll
          for (int r = 0; r < 4; ++r)
            sX[(w * 64 + m * 16 + rb + r) * 20 + r0] = av[r];
        }
      }
      __syncthreads();
      f32x4 gi = *(const f32x4*)&sX[(      bloc) * 20 + j0];
      f32x4 gf = *(const f32x4*)&sX[( 64 + bloc) * 20 + j0];
      f32x4 gg = *(const f32x4*)&sX[(128 + bloc) * 20 + j0];
      f32x4 go = *(const f32x4*)&sX[(192 + bloc) * 20 + j0];
      float cn[4], hn[4], hold[4];
      #pragma unroll
      for (int r = 0; r < 4; ++r) {
        float ci = sigf(gi[r] + bsi[r]);
        float cf = sigf(gf[r] + bsf[r]);
        float cgv = tanh_(gg[r] + bsg[r]);
        float co = sigf(go[r] + bso[r]);
        float c_new = cf * cst[r] + ci * cgv;
        hold[r] = hst[r];
        cst[r] = c_new; cn[r] = c_new;
        hn[r] = co * tanh_(c_new);
      }
      wait_slots(t1base, 8, (unsigned)(t + 1));    // tension(t) + x_{t+1} ready
      float tnraw = ald_f32(&tens[(t & 1) * 256 + pb]);
      float tn = (t < 2) ? 0.f : sigf(tnraw + bt2v);
      float rs = resb[t * 256 + pb];
      float gate = sigf(wg0 * rs + wg1 * tn + bgv);
      const float zt = zeta[t];
      float ho[4];
      #pragma unroll
      for (int r = 0; r < 4; ++r) {
        float hout = hn[r] + gate * (zt * hold[r]);
        hst[r] = hout; ho[r] = hout;
      }
      f16x4 hf;
      #pragma unroll
      for (int r = 0; r < 4; ++r) hf[r] = (f16)ho[r];
      union { f16x4 f; u64 q; } uh; uh.f = hf;
      ast_u64(Anext + (size_t)pb * 768 + 256 + c0 + j0, uh.q);
      post(arrslot, (unsigned)(t + 1));            // h_t visible

      // off-critical-path: output writes
      f32x4 hv = {ho[0], ho[1], ho[2], ho[3]};
      *(f32x4*)(out + ((size_t)pb * 512 + t) * 512 + c0 + j0) = hv;
      if (t == 511) {
        f32x4 cv4 = {cn[0], cn[1], cn[2], cn[3]};
        *(f32x4*)(out + 67108864 + pb * 512 + c0 + j0) = hv;
        *(f32x4*)(out + 67108864 + 131072 + pb * 512 + c0 + j0) = cv4;
      }
      // slack: stage x_{t+1} (guaranteed by t1 >= t+1 wait above) + PGx for t+1
      if (t < 511) {
        u64 lo[8], hi[8];
        #pragma unroll
        for (int i = 0; i < 8; ++i) {
          const int L = i * 256 + tid;
          const int row = L >> 5, c = L & 31;
          const u64* pp = (const u64*)(Anext + (size_t)(m0 + row) * 768 + c * 8);
          lo[i] = ald_u64(pp); hi[i] = ald_u64(pp + 1);
        }
        #pragma unroll
        for (int i = 0; i < 8; ++i) {
          const int L = i * 256 + tid;
          const int row = L >> 5, c = L & 31;
          union { u64 q[2]; uint4 v4; } uq; uq.q[0] = lo[i]; uq.q[1] = hi[i];
          *(uint4*)(sXt + row * 512 + ((c ^ (row & 7)) << 4)) = uq.v4;
        }
        __syncthreads();
        acc0 = (f32x4){0,0,0,0}; acc1 = (f32x4){0,0,0,0};
        acc2 = (f32x4){0,0,0,0}; acc3 = (f32x4){0,0,0,0};
        #pragma unroll
        for (int ks = 0; ks < 8; ++ks) {
          const int cc = ((ks * 4 + kq) ^ lswz) << 4;
          f16x8 q0 = *(const f16x8*)(sXt + (r0     ) * 512 + cc);
          f16x8 q1 = *(const f16x8*)(sXt + (r0 + 16) * 512 + cc);
          f16x8 q2 = *(const f16x8*)(sXt + (r0 + 32) * 512 + cc);
          f16x8 q3 = *(const f16x8*)(sXt + (r0 + 48) * 512 + cc);
          MFMA16(q0, wbx[ks], acc0); MFMA16(q1, wbx[ks], acc1);
          MFMA16(q2, wbx[ks], acc2); MFMA16(q3, wbx[ks], acc3);
        }
      }
    }
  } else {
    // ================= T1 (tension) BLOCK =================
    const int j = bid - NGATE;
    const int p = j >> 3, m0 = p * 64;
    const int q1i = j & 7, n0 = q1i * 64;
    unsigned* slotbase = slots + p * 64 * 32;
    unsigned* myslot   = slotbase + (32 + q1i) * 32;

    f16x8 whm[16], wm[16];
    {
      int row = n0 + w * 16 + r0;
      const f16* WrA = WhmA + (size_t)row * 512 + kq * 8;
      const f16* WrB = WmB  + (size_t)row * 512 + kq * 8;
      #pragma unroll
      for (int ks = 0; ks < 16; ++ks) { whm[ks] = *(const f16x8*)(WrA + ks * 32); wm[ks] = *(const f16x8*)(WrB + ks * 32); }
    }
    float w2a, b1a;
    { int col = n0 + w * 16 + r0; w2a = wt2[col]; b1a = bt1[col]; }

    f32x4 R0[4], R1[4], R2[4], R3[4];
    #pragma unroll
    for (int mi = 0; mi < 4; ++mi) {
      R0[mi] = (f32x4){0,0,0,0}; R1[mi] = (f32x4){0,0,0,0};
      R2[mi] = (f32x4){0,0,0,0}; R3[mi] = (f32x4){0,0,0,0};
    }

    for (int t = 0; t < 512; ++t) {
      const f16* Acur = (t & 1) ? A1 : A0;
      f16* Anext      = (t & 1) ? A0 : A1;

      wait_slots(slotbase, 32, (unsigned)t);       // h_{t-1} ready
      if (q1i == 0 && tid < 64)
        ast_f32(&tens[((t + 1) & 1) * 256 + m0 + tid], 0.f);   // readers of that parity done

      // stage h tile (2 passes of 8)
      #pragma unroll
      for (int pass = 0; pass < 2; ++pass) {
        u64 lo[8], hi[8];
        #pragma unroll
        for (int i = 0; i < 8; ++i) {
          const int L = (pass * 8 + i) * 256 + tid;
          const int row = L >> 6, c = L & 63;
          const u64* pp = (const u64*)(Acur + (size_t)(m0 + row) * 768 + 256 + c * 8);
          lo[i] = ald_u64(pp); hi[i] = ald_u64(pp + 1);
        }
        #pragma unroll
        for (int i = 0; i < 8; ++i) {
          const int L = (pass * 8 + i) * 256 + tid;
          const int row = L >> 6, c = L & 63;
          union { u64 q[2]; uint4 v4; } uq; uq.q[0] = lo[i]; uq.q[1] = hi[i];
          *(uint4*)(sH + row * 1024 + ((c ^ (row & 7)) << 4)) = uq.v4;
        }
      }
      __syncthreads();
      // term1 = h_{t-1} @ (W1h + W1m/5)^T
      f32x4 ta0 = {0,0,0,0}, ta1 = {0,0,0,0}, ta2 = {0,0,0,0}, ta3 = {0,0,0,0};
      #pragma unroll
      for (int ks = 0; ks < 16; ++ks) {
        const int cc = ((ks * 4 + kq) ^ lswz) << 4;
        f16x8 q0 = *(const f16x8*)(sH + (r0     ) * 1024 + cc);
        f16x8 q1 = *(const f16x8*)(sH + (r0 + 16) * 1024 + cc);
        f16x8 q2 = *(const f16x8*)(sH + (r0 + 32) * 1024 + cc);
        f16x8 q3 = *(const f16x8*)(sH + (r0 + 48) * 1024 + cc);
        MFMA16(q0, whm[ks], ta0); MFMA16(q1, whm[ks], ta1);
        MFMA16(q2, whm[ks], ta2); MFMA16(q3, whm[ks], ta3);
      }
      // tension partials: relu(term1 + ring C sums + b1) * w2, reduce over 16 cols
      float* tb = tens + (t & 1) * 256;
      #pragma unroll
      for (int mi = 0; mi < 4; ++mi) {
        f32x4 tv = (mi == 0) ? ta0 : (mi == 1) ? ta1 : (mi == 2) ? ta2 : ta3;
        float sr[4];
        #pragma unroll
        for (int r = 0; r < 4; ++r) {
          float pre = tv[r] + R0[mi][r] + R1[mi][r] + R2[mi][r] + R3[mi][r] + b1a;
          sr[r] = fmaxf(pre, 0.f) * w2a;
        }
        #pragma unroll
        for (int m = 1; m < 16; m <<= 1) {
          #pragma unroll
          for (int r = 0; r < 4; ++r) sr[r] += __shfl_xor(sr[r], m);
        }
        if (r0 == 0) {
          int brow = m0 + mi * 16 + kq * 4;
          #pragma unroll
          for (int r = 0; r < 4; ++r) atomicAdd(&tb[brow + r], sr[r]);
        }
      }
      // x_{t+1} conversion
      if (t < 511) {
        int e = (q1i * 256 + tid) * 8;
        int xb = m0 + (e >> 8), pk = e & 255;
        const float* xp = x + ((size_t)xb * 512 + (t + 1)) * 256 + pk;
        f32x4 xa = *(const f32x4*)xp;
        f32x4 xc = *(const f32x4*)(xp + 4);
        f16x8 xf;
        #pragma unroll
        for (int r = 0; r < 4; ++r) { xf[r] = (f16)xa[r]; xf[4 + r] = (f16)xc[r]; }
        union { f16x8 f; u64 q[2]; } ux; ux.f = xf;
        ast_u64(Anext + (size_t)xb * 768 + pk, ux.q[0]);
        ast_u64(Anext + (size_t)xb * 768 + pk + 4, ux.q[1]);
      }
      post(myslot, (unsigned)(t + 1));             // tension(t) + x_{t+1} visible

      // slack: C_{t-1} = h_{t-1} @ (W1m/5)^T  (reuses staged sH), push into ring
      f32x4 ca0 = {0,0,0,0}, ca1 = {0,0,0,0}, ca2 = {0,0,0,0}, ca3 = {0,0,0,0};
      #pragma unroll
      for (int ks = 0; ks < 16; ++ks) {
        const int cc = ((ks * 4 + kq) ^ lswz) << 4;
        f16x8 q0 = *(const f16x8*)(sH + (r0     ) * 1024 + cc);
        f16x8 q1 = *(const f16x8*)(sH + (r0 + 16) * 1024 + cc);
        f16x8 q2 = *(const f16x8*)(sH + (r0 + 32) * 1024 + cc);
        f16x8 q3 = *(const f16x8*)(sH + (r0 + 48) * 1024 + cc);
        MFMA16(q0, wm[ks], ca0); MFMA16(q1, wm[ks], ca1);
        MFMA16(q2, wm[ks], ca2); MFMA16(q3, wm[ks], ca3);
      }
      #pragma unroll
      for (int mi = 0; mi < 4; ++mi) { R3[mi] = R2[mi]; R2[mi] = R1[mi]; R1[mi] = R0[mi]; }
      R0[0] = ca0; R0[1] = ca1; R0[2] = ca2; R0[3] = ca3;
    }
  }
}

extern "C" void kernel_launch(void* const* d_in, const int* in_sizes, int n_in,
                              void* d_out, int out_size, void* d_ws, size_t ws_size,
                              hipStream_t stream) {
  (void)in_sizes; (void)n_in; (void)out_size; (void)ws_size;
  const float* x     = (const float*)d_in[0];
  const float* Wih   = (const float*)d_in[1];
  const float* Whh   = (const float*)d_in[2];
  const float* bih   = (const float*)d_in[3];
  const float* bhh   = (const float*)d_in[4];
  const float* Wproj = (const float*)d_in[5];
  const float* bproj = (const float*)d_in[6];
  const float* Wt1   = (const float*)d_in[7];
  const float* bt1   = (const float*)d_in[8];
  const float* Wt2   = (const float*)d_in[9];
  const float* bt2   = (const float*)d_in[10];
  const float* Wg    = (const float*)d_in[11];
  const float* bg    = (const float*)d_in[12];
  float* out = (float*)d_out;
  char* ws = (char*)d_ws;
  hipFuncSetAttribute((const void*)k_lstm, hipFuncAttributeMaxDynamicSharedMemorySize, 131072);
  k_init<<<dim3(1024), dim3(256), 0, stream>>>(x, Wih, Whh, bih, bhh, Wt1, ws);
  k_tables<<<dim3(512), dim3(256), 0, stream>>>(Wproj, bproj, ws);
  k_res<<<dim3(32768), dim3(256), 0, stream>>>(x, ws);
  k_lstm<<<dim3(NBLK), dim3(256), 131072, stream>>>(x, bt1, Wt2, bt2, Wg, bg, out, ws);
}

// Round 7
// 4190.842 us; speedup vs baseline: 6.0202x; 1.3339x over previous
//
#include <hip/hip_runtime.h>

typedef _Float16 f16;
typedef _Float16 f16x8 __attribute__((ext_vector_type(8)));
typedef float f32x4 __attribute__((ext_vector_type(4)));
typedef float f32x2 __attribute__((ext_vector_type(2)));
typedef unsigned long long u64;

#define DEVFN static __device__ __forceinline__

#define NBLK 256

// ---------------- workspace layout (bytes) ----------------
#define OFF_WCAT 0ULL                          // 2048*768*2 gates weights [n][k<256:x | k>=256:h]
#define OFF_WT1A (OFF_WCAT + 2048ULL*768*2)    // 512*512*2  (W1h + W1m/5)
#define OFF_WT1B (OFF_WT1A + 512ULL*512*2)     // 512*512*2  (W1m/5)
#define OFF_HB0  (OFF_WT1B + 512ULL*512*2)     // 256*512*2  h parity 0
#define OFF_HB1  (OFF_HB0  + 256ULL*512*2)     // 256*512*2  h parity 1
#define OFF_XB0  (OFF_HB1  + 256ULL*512*2)     // 256*256*2  x mod-3 ring
#define OFF_XB1  (OFF_XB0  + 256ULL*256*2)
#define OFF_XB2  (OFF_XB1  + 256ULL*256*2)
#define OFF_BSUM (OFF_XB2  + 256ULL*256*2)     // 2048*4
#define OFF_U    (OFF_BSUM + 2048ULL*4)
#define OFF_V    (OFF_U    + 512ULL*256*4)
#define OFF_CU   (OFF_V    + 512ULL*256*4)
#define OFF_CV   (OFF_CU   + 512ULL*4)
#define OFF_ZETA (OFF_CV   + 512ULL*4)
#define OFF_RES  (OFF_ZETA + 512ULL*4)         // 512*256*4
#define OFF_TENS (OFF_RES  + 512ULL*256*4)     // 2*256*4
#define OFF_SLOT (OFF_TENS + 2ULL*256*4)       // 8 panels * 64 slots * 128B

__constant__ float CGAM[15] = {14.134725f, 21.02204f, 25.010858f, 30.424876f, 32.935062f,
  37.586178f, 40.91872f, 43.327073f, 48.005151f, 49.773832f, 52.970321f,
  56.446248f, 59.347044f, 60.831779f, 65.112544f};

DEVFN float sigf(float v) { return 1.f / (1.f + __expf(-v)); }
DEVFN float tanh_(float v) {
  v = fminf(fmaxf(v, -15.f), 15.f);
  float e = __expf(2.f * v);
  return (e - 1.f) / (e + 1.f);
}

// ---- fence-free LLC-coherent access helpers ----
DEVFN float ald_f32(const float* p) {
  unsigned v = __hip_atomic_load((const unsigned*)p, __ATOMIC_RELAXED, __HIP_MEMORY_SCOPE_AGENT);
  union { unsigned u; float f; } c; c.u = v; return c.f;
}
DEVFN void ast_f32(float* p, float v) {
  union { float f; unsigned u; } c; c.f = v;
  __hip_atomic_store((unsigned*)p, c.u, __ATOMIC_RELAXED, __HIP_MEMORY_SCOPE_AGENT);
}
DEVFN u64 ald_u64(const void* p) {
  return __hip_atomic_load((const u64*)p, __ATOMIC_RELAXED, __HIP_MEMORY_SCOPE_AGENT);
}
DEVFN void ast_u32(void* p, unsigned v) {
  __hip_atomic_store((unsigned*)p, v, __ATOMIC_RELAXED, __HIP_MEMORY_SCOPE_AGENT);
}

// producer: all waves drain own vmem, converge, one relaxed slot store
DEVFN void post(unsigned* slot, unsigned v) {
  asm volatile("s_waitcnt vmcnt(0)" ::: "memory");
  __syncthreads();
  if (threadIdx.x == 0)
    __hip_atomic_store(slot, v, __ATOMIC_RELAXED, __HIP_MEMORY_SCOPE_AGENT);
}
// consumer: wave0 gathers n slots (one lane each), exits when all >= target
DEVFN void wait_slots(const unsigned* base, int n, unsigned target) {
  if (threadIdx.x < 64) {
    const unsigned* pp = base + (threadIdx.x < n ? threadIdx.x : 0) * 32;
    const bool mine = threadIdx.x < n;
    long sp = 0;
    for (;;) {
      unsigned v = __hip_atomic_load(pp, __ATOMIC_RELAXED, __HIP_MEMORY_SCOPE_AGENT);
      bool ok = (!mine) || (v >= target);
      if (__all(ok)) break;
      __builtin_amdgcn_s_sleep(1);
      if (++sp > (1L << 21)) break;
    }
  }
  __syncthreads();
}

// ---------------- init ----------------
__global__ void k_init(const float* __restrict__ x, const float* __restrict__ Wih,
                       const float* __restrict__ Whh, const float* __restrict__ bih,
                       const float* __restrict__ bhh, const float* __restrict__ Wt1f,
                       char* __restrict__ ws) {
  f16* Wcat = (f16*)(ws + OFF_WCAT);
  f16* WhmA = (f16*)(ws + OFF_WT1A);
  f16* WmB  = (f16*)(ws + OFF_WT1B);
  f16* hb0  = (f16*)(ws + OFF_HB0);
  f16* xb0  = (f16*)(ws + OFF_XB0);
  f16* xb1  = (f16*)(ws + OFF_XB1);
  float* bsum = (float*)(ws + OFF_BSUM);
  float* tens = (float*)(ws + OFF_TENS);
  unsigned* slots = (unsigned*)(ws + OFF_SLOT);
  int gtid = blockIdx.x * blockDim.x + threadIdx.x;
  int nth = gridDim.x * blockDim.x;
  for (int i = gtid; i < 2048 * 768; i += nth) {
    int n = i / 768, k = i - n * 768;
    float w = (k < 256) ? Wih[n * 256 + k] : Whh[n * 512 + (k - 256)];
    Wcat[i] = (f16)w;
  }
  for (int i = gtid; i < 512 * 512; i += nth) {
    int n = i >> 9, k = i & 511;
    float wh = Wt1f[n * 1024 + k];
    float wm = Wt1f[n * 1024 + 512 + k] * 0.2f;
    WhmA[i] = (f16)(wh + wm);
    WmB[i]  = (f16)wm;
  }
  for (int i = gtid; i < 2048; i += nth) bsum[i] = bih[i] + bhh[i];
  for (int i = gtid; i < 256 * 512; i += nth) hb0[i] = (f16)0.f;
  for (int i = gtid; i < 256 * 256; i += nth) {
    int b = i >> 8, k = i & 255;
    xb0[i] = (f16)x[(size_t)b * 131072 + k];
    xb1[i] = (f16)x[(size_t)b * 131072 + 256 + k];
  }
  for (int i = gtid; i < 512; i += nth) tens[i] = 0.f;
  for (int i = gtid; i < 8 * 64 * 32; i += nth) slots[i] = 0u;
}

// ---------------- per-t tables ----------------
__global__ void k_tables(const float* __restrict__ Wproj, const float* __restrict__ bproj,
                         char* __restrict__ ws) {
  float* u    = (float*)(ws + OFF_U);
  float* v    = (float*)(ws + OFF_V);
  float* cu   = (float*)(ws + OFF_CU);
  float* cv   = (float*)(ws + OFF_CV);
  float* zeta = (float*)(ws + OFF_ZETA);
  int t = blockIdx.x;
  int k = threadIdx.x;
  float tf = (float)t;
  float cg[15], sg[15], ph[15];
  #pragma unroll
  for (int m = 0; m < 15; ++m) {
    float ang = CGAM[m] * tf;
    cg[m] = cosf(ang);
    sg[m] = sinf(ang);
    ph[m] = (float)exp(-0.1 * (double)CGAM[m]);
  }
  float uu = 0.f, vv = 0.f;
  #pragma unroll
  for (int m = 0; m < 15; ++m) {
    uu += Wproj[m * 256 + k] * cg[m] * ph[m];
    vv += Wproj[(15 + m) * 256 + k] * sg[m] * ph[m];
  }
  u[t * 256 + k] = uu;
  v[t * 256 + k] = vv;
  if (k == 0) {
    float a = 0.f, b2 = 0.f, z = 0.f;
    #pragma unroll
    for (int m = 0; m < 15; ++m) {
      a  += bproj[m] * cg[m] * ph[m];
      b2 += bproj[15 + m] * sg[m] * ph[m];
      z  += ph[m] * cg[m];
    }
    cu[t] = a; cv[t] = b2; zeta[t] = z / 15.f;
  }
}

// ---------------- resonance precompute ----------------
__global__ void k_res(const float* __restrict__ x, char* __restrict__ ws) {
  const float* u  = (const float*)(ws + OFF_U);
  const float* v  = (const float*)(ws + OFF_V);
  const float* cu = (const float*)(ws + OFF_CU);
  const float* cv = (const float*)(ws + OFF_CV);
  float* resb     = (float*)(ws + OFF_RES);
  int wid = blockIdx.x * 4 + (threadIdx.x >> 6);
  int l = threadIdx.x & 63;
  int b = wid >> 9, t = wid & 511;
  const f32x4 xx = *(const f32x4*)(x + ((size_t)(b * 512 + t)) * 256 + l * 4);
  const f32x4 uu = *(const f32x4*)(u + t * 256 + l * 4);
  const f32x4 vv = *(const f32x4*)(v + t * 256 + l * 4);
  float cc = xx[0]*uu[0] + xx[1]*uu[1] + xx[2]*uu[2] + xx[3]*uu[3];
  float ss = xx[0]*vv[0] + xx[1]*vv[1] + xx[2]*vv[2] + xx[3]*vv[3];
  #pragma unroll
  for (int m = 1; m < 64; m <<= 1) { cc += __shfl_xor(cc, m); ss += __shfl_xor(ss, m); }
  if (l == 0) {
    cc += cu[t]; ss += cv[t];
    float r = sqrtf(cc * cc + ss * ss + 1e-8f) - 0.5f;
    resb[t * 256 + b] = sigf(r);
  }
}

#define MFMA16(qv, wv, av) av = __builtin_amdgcn_mfma_f32_16x16x32_f16(qv, wv, av, 0, 0, 0)

// ---------------- persistent fused recurrent kernel (256 blocks, uniform) ----------------
__global__ void __launch_bounds__(256, 1)
k_lstm(const float* __restrict__ x, const float* __restrict__ bt1,
       const float* __restrict__ wt2, const float* __restrict__ bt2,
       const float* __restrict__ wg, const float* __restrict__ bg,
       float* __restrict__ out, char* __restrict__ ws) {
  extern __shared__ char lds[];
  char*  sH  = lds;                       // 32 KB  h tile [32][512] f16 swizzled
  char*  sXt = lds + 32768;               // 16 KB  x tile [32][256] f16 swizzled
  char*  sWx = lds + 49152;               // 32 KB  x-weights per wave [4][16][256]
  float* sT  = (float*)(lds + 81920);     //  8 KB  tension partial exchange [4][512]
  float* sX  = (float*)(lds + 90112);     // 10 KB  gate exchange [4][32][20] f32

  const f16* __restrict__ Wcat = (const f16*)(ws + OFF_WCAT);
  const f16* __restrict__ WhmA = (const f16*)(ws + OFF_WT1A);
  const f16* __restrict__ WmB  = (const f16*)(ws + OFF_WT1B);
  f16* hb[2] = { (f16*)(ws + OFF_HB0), (f16*)(ws + OFF_HB1) };
  f16* xb[3] = { (f16*)(ws + OFF_XB0), (f16*)(ws + OFF_XB1), (f16*)(ws + OFF_XB2) };
  const float* bsum = (const float*)(ws + OFF_BSUM);
  const float* zeta = (const float*)(ws + OFF_ZETA);
  const float* resb = (const float*)(ws + OFF_RES);
  float* tens  = (float*)(ws + OFF_TENS);
  unsigned* slots = (unsigned*)(ws + OFF_SLOT);

  const int tid = threadIdx.x;
  const int w = tid >> 6, l = tid & 63;
  const int r0 = l & 15, kq = l >> 4;
  const int bid = blockIdx.x;
  const int p = bid >> 5, q = bid & 31;
  const int c0 = q * 16, m0 = p * 32;

  unsigned* slotHb = slots + p * 2048;
  unsigned* slotTb = slotHb + 1024;
  unsigned* myH = slotHb + q * 32;
  unsigned* myT = slotTb + q * 32;

  // ---- fill sWx (x-part gate weights, per-wave slice, swizzled) ----
  #pragma unroll
  for (int i = 0; i < 8; ++i) {
    const int B = i * 256 + tid;
    const int w_ = B >> 9, row = (B >> 5) & 15, c = B & 31;
    uint4 v4 = *(const uint4*)(Wcat + (size_t)(w_ * 512 + c0 + row) * 768 + c * 8);
    *(uint4*)(sWx + w_ * 8192 + row * 512 + ((c ^ (row & 7)) << 4)) = v4;
  }

  // ---- persistent weight fragments ----
  f16x8 wbh[16];               // h-part gate weights (wave = gate type, 16 cols)
  {
    const f16* Wr = Wcat + (size_t)(w * 512 + c0 + r0) * 768 + 256 + kq * 8;
    #pragma unroll
    for (int ks = 0; ks < 16; ++ks) wbh[ks] = *(const f16x8*)(Wr + ks * 32);
  }
  f16x8 wbhm[4], wbm[4];       // tension weights, K-split: wave w owns k in [w*128, w*128+128)
  {
    const f16* Wa = WhmA + (size_t)(q * 16 + r0) * 512 + w * 128 + kq * 8;
    const f16* Wb = WmB  + (size_t)(q * 16 + r0) * 512 + w * 128 + kq * 8;
    #pragma unroll
    for (int ks = 0; ks < 4; ++ks) {
      wbhm[ks] = *(const f16x8*)(Wa + ks * 32);
      wbm[ks]  = *(const f16x8*)(Wb + ks * 32);
    }
  }
  const float b1a = bt1[q * 16 + r0], w2a = wt2[q * 16 + r0];

  // ---- per-thread pointwise state: batch b_loc, cols c0+c_loc, c0+c_loc+1 ----
  const int b_loc = tid >> 3, c_loc = (tid & 7) * 2;
  const int pb = m0 + b_loc;
  float bsv[4][2];
  #pragma unroll
  for (int g = 0; g < 4; ++g) {
    bsv[g][0] = bsum[g * 512 + c0 + c_loc];
    bsv[g][1] = bsum[g * 512 + c0 + c_loc + 1];
  }
  const float wg0 = wg[0], wg1 = wg[1], bt2v = bt2[0], bgv = bg[0];
  float cst[2] = {0.f, 0.f}, hst[2] = {0.f, 0.f};

  // ring of per-wave K-slice C partials (hmean contributions of h_{t-2}..h_{t-5})
  f32x4 R[4][2];
  #pragma unroll
  for (int s = 0; s < 4; ++s) { R[s][0] = (f32x4){0,0,0,0}; R[s][1] = (f32x4){0,0,0,0}; }

  // ---- prologue: stage x_0, PGx into pa ----
  f32x4 pa0 = {0,0,0,0}, pa1 = {0,0,0,0};
  {
    u64 lo[4], hi[4];
    #pragma unroll
    for (int i = 0; i < 4; ++i) {
      const int B = i * 256 + tid;
      const int row = B >> 5, c = B & 31;
      const u64* pp = (const u64*)(xb[0] + (size_t)(m0 + row) * 256 + c * 8);
      lo[i] = ald_u64(pp); hi[i] = ald_u64(pp + 1);
    }
    #pragma unroll
    for (int i = 0; i < 4; ++i) {
      const int B = i * 256 + tid;
      const int row = B >> 5, c = B & 31;
      union { u64 qq[2]; uint4 v4; } uq; uq.qq[0] = lo[i]; uq.qq[1] = hi[i];
      *(uint4*)(sXt + row * 512 + ((c ^ (row & 7)) << 4)) = uq.v4;
    }
    __syncthreads();
    #pragma unroll
    for (int ks = 0; ks < 8; ++ks) {
      const int cc = (((ks * 4 + kq) ^ (r0 & 7)) << 4);
      f16x8 a0 = *(const f16x8*)(sXt + r0 * 512 + cc);
      f16x8 a1 = *(const f16x8*)(sXt + (r0 + 16) * 512 + cc);
      f16x8 bx = *(const f16x8*)(sWx + w * 8192 + r0 * 512 + cc);
      MFMA16(a0, bx, pa0); MFMA16(a1, bx, pa1);
    }
  }

  for (int t = 0; t < 512; ++t) {
    const int cur = t & 1, nxt = cur ^ 1;
    const f16* hsrc = hb[cur];

    wait_slots(slotHb, 32, (unsigned)t);        // h_{t-1} visible (t=0 trivially)

    // ---- stage h tile (32 KB, single flight) + issue early x load (waves 2-3) ----
    u64 lo[8], hi[8];
    #pragma unroll
    for (int i = 0; i < 8; ++i) {
      const int B = i * 256 + tid;
      const int row = B >> 6, c = B & 63;
      const u64* pp = (const u64*)(hsrc + (size_t)(m0 + row) * 512 + c * 8);
      lo[i] = ald_u64(pp); hi[i] = ald_u64(pp + 1);
    }
    f32x2 xv = {0.f, 0.f};
    if (tid >= 128 && t < 510)
      xv = *(const f32x2*)(x + ((size_t)(m0 + q) * 512 + (t + 2)) * 256 + (tid - 128) * 2);
    #pragma unroll
    for (int i = 0; i < 8; ++i) {
      const int B = i * 256 + tid;
      const int row = B >> 6, c = B & 63;
      union { u64 qq[2]; uint4 v4; } uq; uq.qq[0] = lo[i]; uq.qq[1] = hi[i];
      *(uint4*)(sH + row * 1024 + ((c ^ (row & 7)) << 4)) = uq.v4;
    }
    __syncthreads();

    // ---- tension term1 (K-split per wave) + ring partials -> sT ----
    f32x4 ta0 = {0,0,0,0}, ta1 = {0,0,0,0};
    #pragma unroll
    for (int ks = 0; ks < 4; ++ks) {
      const int cc = ((((w * 4 + ks) * 4 + kq) ^ (r0 & 7)) << 4);
      f16x8 q0 = *(const f16x8*)(sH + r0 * 1024 + cc);
      f16x8 q1 = *(const f16x8*)(sH + (r0 + 16) * 1024 + cc);
      MFMA16(q0, wbhm[ks], ta0); MFMA16(q1, wbhm[ks], ta1);
    }
    {
      f32x4 s0 = ta0 + R[0][0] + R[1][0] + R[2][0] + R[3][0];
      f32x4 s1 = ta1 + R[0][1] + R[1][1] + R[2][1] + R[3][1];
      *(f32x4*)(sT + w * 512 + l * 8) = s0;
      *(f32x4*)(sT + w * 512 + l * 8 + 4) = s1;
    }
    __syncthreads();
    if (w == 0) {            // wave 0: sum partials, relu*w2, 16-lane reduce, atomics, post
      float sr0[4], sr1[4];
      #pragma unroll
      for (int r = 0; r < 4; ++r) {
        float p0 = sT[l*8 + r] + sT[512 + l*8 + r] + sT[1024 + l*8 + r] + sT[1536 + l*8 + r] + b1a;
        float p1 = sT[l*8 + 4 + r] + sT[512 + l*8 + 4 + r] + sT[1024 + l*8 + 4 + r] + sT[1536 + l*8 + 4 + r] + b1a;
        sr0[r] = fmaxf(p0, 0.f) * w2a;
        sr1[r] = fmaxf(p1, 0.f) * w2a;
      }
      #pragma unroll
      for (int m = 1; m < 16; m <<= 1) {
        #pragma unroll
        for (int r = 0; r < 4; ++r) { sr0[r] += __shfl_xor(sr0[r], m); sr1[r] += __shfl_xor(sr1[r], m); }
      }
      if (r0 == 0) {
        float* tb = tens + cur * 256 + m0 + kq * 4;
        #pragma unroll
        for (int r = 0; r < 4; ++r) { atomicAdd(&tb[r], sr0[r]); atomicAdd(&tb[16 + r], sr1[r]); }
      }
      asm volatile("s_waitcnt vmcnt(0)" ::: "memory");
      if (tid == 0)
        __hip_atomic_store(myT, (unsigned)(t + 1), __ATOMIC_RELAXED, __HIP_MEMORY_SCOPE_AGENT);
    }

    // ---- gate h-GEMM (K=512) accumulating onto PGx ----
    #pragma unroll
    for (int ks = 0; ks < 16; ++ks) {
      const int cc = (((ks * 4 + kq) ^ (r0 & 7)) << 4);
      f16x8 q0 = *(const f16x8*)(sH + r0 * 1024 + cc);
      f16x8 q1 = *(const f16x8*)(sH + (r0 + 16) * 1024 + cc);
      MFMA16(q0, wbh[ks], pa0); MFMA16(q1, wbh[ks], pa1);
    }
    // ---- exchange: acc -> sX ----
    {
      const int rb = kq * 4;
      #pragma unroll
      for (int r = 0; r < 4; ++r) {
        sX[(w * 32 + rb + r) * 20 + r0]      = pa0[r];
        sX[(w * 32 + 16 + rb + r) * 20 + r0] = pa1[r];
      }
    }
    __syncthreads();
    // ---- pointwise LSTM (2 elements / thread) ----
    float cn[2], hn[2], hold[2];
    #pragma unroll
    for (int e = 0; e < 2; ++e) {
      float gi = sX[(       b_loc) * 20 + c_loc + e] + bsv[0][e];
      float gf = sX[( 32 + b_loc) * 20 + c_loc + e] + bsv[1][e];
      float gg = sX[( 64 + b_loc) * 20 + c_loc + e] + bsv[2][e];
      float go = sX[( 96 + b_loc) * 20 + c_loc + e] + bsv[3][e];
      float c_new = sigf(gf) * cst[e] + sigf(gi) * tanh_(gg);
      hold[e] = hst[e];
      cst[e] = c_new; cn[e] = c_new;
      hn[e] = sigf(go) * tanh_(c_new);
    }
    wait_slots(slotTb, 32, (unsigned)(t + 1));   // all tension partials in
    float tnraw = ald_f32(&tens[cur * 256 + pb]);
    float tn = (t < 2) ? 0.f : sigf(tnraw + bt2v);
    float rs = resb[t * 256 + pb];
    float gate = sigf(wg0 * rs + wg1 * tn + bgv);
    const float zt = zeta[t];
    float ho[2];
    #pragma unroll
    for (int e = 0; e < 2; ++e) { ho[e] = hn[e] + gate * (zt * hold[e]); hst[e] = ho[e]; }

    // ---- pre-post stores: h_t, tens clear, x_{t+2} f16 ----
    {
      union { f16 h2[2]; unsigned u; } ph_;
      ph_.h2[0] = (f16)ho[0]; ph_.h2[1] = (f16)ho[1];
      ast_u32(hb[nxt] + (size_t)pb * 512 + c0 + c_loc, ph_.u);
    }
    if (tid == 0) ast_f32(&tens[nxt * 256 + m0 + q], 0.f);
    if (tid >= 128 && t < 510) {
      union { f16 h2[2]; unsigned u; } px;
      px.h2[0] = (f16)xv[0]; px.h2[1] = (f16)xv[1];
      ast_u32(xb[(t + 2) % 3] + (size_t)(m0 + q) * 256 + (tid - 128) * 2, px.u);
    }
    post(myH, (unsigned)(t + 1));

    // ---- slack: outputs + next-step x stage + PGx + ring-C GEMM ----
    f32x2 ov = {ho[0], ho[1]};
    *(f32x2*)(out + ((size_t)pb * 512 + t) * 512 + c0 + c_loc) = ov;
    if (t == 511) {
      f32x2 cv2 = {cn[0], cn[1]};
      *(f32x2*)(out + 67108864 + (size_t)pb * 512 + c0 + c_loc) = ov;
      *(f32x2*)(out + 67108864 + 131072 + (size_t)pb * 512 + c0 + c_loc) = cv2;
    } else {
      const f16* xsrc = xb[(t + 1) % 3];
      u64 xlo[4], xhi[4];
      #pragma unroll
      for (int i = 0; i < 4; ++i) {
        const int B = i * 256 + tid;
        const int row = B >> 5, c = B & 31;
        const u64* pp = (const u64*)(xsrc + (size_t)(m0 + row) * 256 + c * 8);
        xlo[i] = ald_u64(pp); xhi[i] = ald_u64(pp + 1);
      }
      #pragma unroll
      for (int i = 0; i < 4; ++i) {
        const int B = i * 256 + tid;
        const int row = B >> 5, c = B & 31;
        union { u64 qq[2]; uint4 v4; } uq; uq.qq[0] = xlo[i]; uq.qq[1] = xhi[i];
        *(uint4*)(sXt + row * 512 + ((c ^ (row & 7)) << 4)) = uq.v4;
      }
      __syncthreads();
      pa0 = (f32x4){0,0,0,0}; pa1 = (f32x4){0,0,0,0};
      #pragma unroll
      for (int ks = 0; ks < 8; ++ks) {
        const int cc = (((ks * 4 + kq) ^ (r0 & 7)) << 4);
        f16x8 a0 = *(const f16x8*)(sXt + r0 * 512 + cc);
        f16x8 a1 = *(const f16x8*)(sXt + (r0 + 16) * 512 + cc);
        f16x8 bx = *(const f16x8*)(sWx + w * 8192 + r0 * 512 + cc);
        MFMA16(a0, bx, pa0); MFMA16(a1, bx, pa1);
      }
      // ring-C: this step's h tile contributes to hmean of steps t+2..t+5 (K-slice per wave)
      f32x4 ca0 = {0,0,0,0}, ca1 = {0,0,0,0};
      #pragma unroll
      for (int ks = 0; ks < 4; ++ks) {
        const int cc = ((((w * 4 + ks) * 4 + kq) ^ (r0 & 7)) << 4);
        f16x8 q0 = *(const f16x8*)(sH + r0 * 1024 + cc);
        f16x8 q1 = *(const f16x8*)(sH + (r0 + 16) * 1024 + cc);
        MFMA16(q0, wbm[ks], ca0); MFMA16(q1, wbm[ks], ca1);
      }
      #pragma unroll
      for (int s = 3; s > 0; --s) { R[s][0] = R[s-1][0]; R[s][1] = R[s-1][1]; }
      R[0][0] = ca0; R[0][1] = ca1;
    }
  }
}

extern "C" void kernel_launch(void* const* d_in, const int* in_sizes, int n_in,
                              void* d_out, int out_size, void* d_ws, size_t ws_size,
                              hipStream_t stream) {
  (void)in_sizes; (void)n_in; (void)out_size; (void)ws_size;
  const float* x     = (const float*)d_in[0];
  const float* Wih   = (const float*)d_in[1];
  const float* Whh   = (const float*)d_in[2];
  const float* bih   = (const float*)d_in[3];
  const float* bhh   = (const float*)d_in[4];
  const float* Wproj = (const float*)d_in[5];
  const float* bproj = (const float*)d_in[6];
  const float* Wt1   = (const float*)d_in[7];
  const float* bt1   = (const float*)d_in[8];
  const float* Wt2   = (const float*)d_in[9];
  const float* bt2   = (const float*)d_in[10];
  const float* Wg    = (const float*)d_in[11];
  const float* bg    = (const float*)d_in[12];
  float* out = (float*)d_out;
  char* ws = (char*)d_ws;
  hipFuncSetAttribute((const void*)k_lstm, hipFuncAttributeMaxDynamicSharedMemorySize, 131072);
  k_init<<<dim3(1024), dim3(256), 0, stream>>>(x, Wih, Whh, bih, bhh, Wt1, ws);
  k_tables<<<dim3(512), dim3(256), 0, stream>>>(Wproj, bproj, ws);
  k_res<<<dim3(32768), dim3(256), 0, stream>>>(x, ws);
  k_lstm<<<dim3(NBLK), dim3(256), 100352, stream>>>(x, bt1, Wt2, bt2, Wg, bg, out, ws);
}